// Round 5
// baseline (181.009 us; speedup 1.0000x reference)
//
#include <hip/hip_runtime.h>

typedef __attribute__((ext_vector_type(8))) short bf16x8;
typedef __attribute__((ext_vector_type(4))) float f32x4;
typedef __attribute__((ext_vector_type(4))) unsigned short u16x4;
typedef __attribute__((ext_vector_type(8))) unsigned short u16x8;

#define MFMA16(a, b, c) __builtin_amdgcn_mfma_f32_16x16x32_bf16((a), (b), (c), 0, 0, 0)

__device__ __forceinline__ ushort f2bf(float f) {
    unsigned u = __float_as_uint(f);
    unsigned r = (u + 0x7FFFu + ((u >> 16) & 1u)) >> 16;
    return (ushort)r;
}
__device__ __forceinline__ float bf2f(ushort s) {
    return __uint_as_float(((unsigned)s) << 16);
}

// async global->LDS, 16B per lane. LDS dest is wave-uniform base + lane*16.
__device__ __forceinline__ void async16(const ushort* g, ushort* l) {
    __builtin_amdgcn_global_load_lds(
        (const __attribute__((address_space(1))) unsigned*)g,
        (__attribute__((address_space(3))) unsigned*)l, 16, 0, 0);
}

#define SBAR()  __builtin_amdgcn_s_barrier()
#define SCHED() __builtin_amdgcn_sched_barrier(0)

// ---------------------------------------------------------------------------
// Kernel 0a: straight fp32 -> bf16 conversion of x (8192x1024) and Wv (1024x1024).
// ---------------------------------------------------------------------------
__global__ __launch_bounds__(256) void cvt_bf16(
    const float* __restrict__ x, const float* __restrict__ wv,
    ushort* __restrict__ xb, ushort* __restrict__ wvb)
{
    const size_t XN = (size_t)8192 * 1024;
    size_t idx = ((size_t)blockIdx.x * 256 + threadIdx.x) * 8;
    const float* s;
    ushort* d;
    if (idx < XN) { s = x + idx; d = xb + idx; }
    else          { s = wv + (idx - XN); d = wvb + (idx - XN); }
    float4 a = *(const float4*)s;
    float4 b = *(const float4*)(s + 4);
    u16x8 p;
    p[0] = f2bf(a.x); p[1] = f2bf(a.y); p[2] = f2bf(a.z); p[3] = f2bf(a.w);
    p[4] = f2bf(b.x); p[5] = f2bf(b.y); p[6] = f2bf(b.z); p[7] = f2bf(b.w);
    *(u16x8*)d = p;
}

// ---------------------------------------------------------------------------
// Kernel 0b: transposing fp32 -> bf16 for Wk and Wq: out[d][e] = in[e][d].
// ---------------------------------------------------------------------------
__global__ __launch_bounds__(256) void cvt_transpose(
    const float* __restrict__ w0, const float* __restrict__ w1,
    ushort* __restrict__ t0, ushort* __restrict__ t1)
{
    const float* src = blockIdx.z ? w1 : w0;
    ushort*      dst = blockIdx.z ? t1 : t0;
    __shared__ float t[32][33];
    const int e0 = blockIdx.x * 32, d0 = blockIdx.y * 32;
    const int tx = threadIdx.x, ty = threadIdx.y;
#pragma unroll
    for (int r = 0; r < 4; ++r)
        t[ty + 8 * r][tx] = src[(size_t)(e0 + ty + 8 * r) * 1024 + d0 + tx];
    __syncthreads();
#pragma unroll
    for (int r = 0; r < 4; ++r)
        dst[(size_t)(d0 + ty + 8 * r) * 1024 + e0 + tx] = f2bf(t[tx][ty + 8 * r]);
}

// ---------------------------------------------------------------------------
// 2-phase 128x128 core (kept for m_gemm). 256 threads.
// ---------------------------------------------------------------------------
__device__ __forceinline__ void mma_tile(
    const ushort* __restrict__ A, int lda, int abase,
    const ushort* __restrict__ B, int ldb, int bbase,
    int ktiles,
    ushort* As, ushort* Bs, f32x4 (&acc)[4][4])
{
    const int tid  = threadIdx.x;
    const int lane = tid & 63, wid = tid >> 6;
    const int wr = wid >> 1, wc = wid & 1;
    const int lrow = lane & 15, kgrp = lane >> 4;
    const int ci = lane >> 3;
    const int cc = (lane & 7) * 8;

#pragma unroll
    for (int m = 0; m < 4; ++m)
#pragma unroll
        for (int n = 0; n < 4; ++n) acc[m][n] = (f32x4){0.f, 0.f, 0.f, 0.f};

    for (int kt = 0; kt < ktiles; ++kt) {
        const int k0 = kt * 64;
#pragma unroll
        for (int i = 0; i < 4; ++i) {
            const int r = (wid * 4 + i) * 8 + ci;
            async16(&A[(size_t)(abase + r) * lda + k0 + cc], &As[(wid * 4 + i) * 512]);
            async16(&B[(size_t)(bbase + r) * ldb + k0 + cc], &Bs[(wid * 4 + i) * 512]);
        }
        __syncthreads();
#pragma unroll
        for (int kk = 0; kk < 2; ++kk) {
            bf16x8 af[4], bfr[4];
#pragma unroll
            for (int m = 0; m < 4; ++m)
                af[m] = *(const bf16x8*)&As[(wr * 64 + m * 16 + lrow) * 64 + kk * 32 + kgrp * 8];
#pragma unroll
            for (int n = 0; n < 4; ++n)
                bfr[n] = *(const bf16x8*)&Bs[(wc * 64 + n * 16 + lrow) * 64 + kk * 32 + kgrp * 8];
#pragma unroll
            for (int m = 0; m < 4; ++m)
#pragma unroll
                for (int n = 0; n < 4; ++n)
                    acc[m][n] = MFMA16(af[m], bfr[n], acc[m][n]);
        }
        __syncthreads();
    }
}

// ---------------------------------------------------------------------------
// 8-phase 256x256 core. 512 threads = 8 waves (2 Mrows x 4 Ncols).
// See round-3 ledger; vmcnt(4) per K-tile (A:2+2, B:2+2 loads/thread/tile).
// ---------------------------------------------------------------------------
__device__ __forceinline__ void mma256(
    const ushort* __restrict__ A, int lda, int abase,
    const ushort* __restrict__ B, int ldb, int bbase,
    int NT, ushort* As, ushort* Bs, f32x4 (&acc)[8][4])
{
    const int tid  = threadIdx.x;
    const int lane = tid & 63, w = tid >> 6;
    const int wr = w >> 2, wc = w & 3;
    const int lrow = lane & 15, kgrp = lane >> 4;
    const int srr = lane >> 2;          // staging row within 16-row group
    const int scc = (lane & 3) * 8;     // staging col (elems)

    auto stage = [&](int t, int isB, int kk) {
        const ushort* src = isB ? B : A;
        const int ld = isB ? ldb : lda;
        const int rb = isB ? bbase : abase;
        ushort* slot = (isB ? Bs : As) + (size_t)(((t & 1) * 2 + kk)) * 8192;
#pragma unroll
        for (int i = 0; i < 2; ++i) {
            const int r = (w * 2 + i) * 16 + srr;
            async16(&src[(size_t)(rb + r) * ld + t * 64 + kk * 32 + scc],
                    slot + (w * 2 + i) * 512);
        }
    };

#pragma unroll
    for (int m = 0; m < 8; ++m)
#pragma unroll
        for (int n = 0; n < 4; ++n) acc[m][n] = (f32x4){0.f, 0.f, 0.f, 0.f};

    stage(0, 0, 0); stage(0, 1, 0); stage(0, 0, 1); stage(0, 1, 1);
    if (NT > 1) {
        stage(1, 0, 0); stage(1, 1, 0);
        asm volatile("s_waitcnt vmcnt(4)" ::: "memory");
    } else {
        asm volatile("s_waitcnt vmcnt(0)" ::: "memory");
    }
    SCHED();
    SBAR();
    SCHED();

    for (int t = 0; t < NT; ++t) {
        ushort* Ab = As + (size_t)(t & 1) * 2 * 8192;
        ushort* Bb = Bs + (size_t)(t & 1) * 2 * 8192;
        bf16x8 af[8], bfr[2];

        // ---- P1: (kk0, n0-1) ----
#pragma unroll
        for (int m = 0; m < 8; ++m)
            af[m] = *(const bf16x8*)&Ab[(wr * 128 + m * 16 + lrow) * 32 + kgrp * 8];
#pragma unroll
        for (int n = 0; n < 2; ++n)
            bfr[n] = *(const bf16x8*)&Bb[(wc * 64 + n * 16 + lrow) * 32 + kgrp * 8];
        if (t + 1 < NT) stage(t + 1, 0, 1);
        SBAR(); SCHED();
        __builtin_amdgcn_s_setprio(1);
#pragma unroll
        for (int m = 0; m < 8; ++m) {
            acc[m][0] = MFMA16(af[m], bfr[0], acc[m][0]);
            acc[m][1] = MFMA16(af[m], bfr[1], acc[m][1]);
        }
        __builtin_amdgcn_s_setprio(0);
        SBAR(); SCHED();

        // ---- P2: (kk0, n2-3) ----
#pragma unroll
        for (int n = 0; n < 2; ++n)
            bfr[n] = *(const bf16x8*)&Bb[(wc * 64 + (2 + n) * 16 + lrow) * 32 + kgrp * 8];
        if (t + 1 < NT) stage(t + 1, 1, 1);
        SBAR(); SCHED();
        __builtin_amdgcn_s_setprio(1);
#pragma unroll
        for (int m = 0; m < 8; ++m) {
            acc[m][2] = MFMA16(af[m], bfr[0], acc[m][2]);
            acc[m][3] = MFMA16(af[m], bfr[1], acc[m][3]);
        }
        __builtin_amdgcn_s_setprio(0);
        SBAR(); SCHED();

        // ---- P3: (kk1, n0-1) ----
#pragma unroll
        for (int m = 0; m < 8; ++m)
            af[m] = *(const bf16x8*)&Ab[8192 + (wr * 128 + m * 16 + lrow) * 32 + kgrp * 8];
#pragma unroll
        for (int n = 0; n < 2; ++n)
            bfr[n] = *(const bf16x8*)&Bb[8192 + (wc * 64 + n * 16 + lrow) * 32 + kgrp * 8];
        if (t + 2 < NT) stage(t + 2, 0, 0);
        SBAR(); SCHED();
        __builtin_amdgcn_s_setprio(1);
#pragma unroll
        for (int m = 0; m < 8; ++m) {
            acc[m][0] = MFMA16(af[m], bfr[0], acc[m][0]);
            acc[m][1] = MFMA16(af[m], bfr[1], acc[m][1]);
        }
        __builtin_amdgcn_s_setprio(0);
        SBAR(); SCHED();

        // ---- P4: (kk1, n2-3) ----
#pragma unroll
        for (int n = 0; n < 2; ++n)
            bfr[n] = *(const bf16x8*)&Bb[8192 + (wc * 64 + (2 + n) * 16 + lrow) * 32 + kgrp * 8];
        if (t + 2 < NT) {
            stage(t + 2, 1, 0);
            asm volatile("s_waitcnt vmcnt(4)" ::: "memory");
        } else if (t + 1 < NT) {
            asm volatile("s_waitcnt vmcnt(0)" ::: "memory");
        }
        SCHED();
        SBAR(); SCHED();
        __builtin_amdgcn_s_setprio(1);
#pragma unroll
        for (int m = 0; m < 8; ++m) {
            acc[m][2] = MFMA16(af[m], bfr[0], acc[m][2]);
            acc[m][3] = MFMA16(af[m], bfr[1], acc[m][3]);
        }
        __builtin_amdgcn_s_setprio(0);
        SBAR(); SCHED();
    }
}

// ---------------------------------------------------------------------------
// 8-phase 256x128 core for PV. 512 threads = 8 waves (2 Mrows x 4 Ncols of 32).
// LDS: As 2buf x 2kk x [256][32] (64 KiB), Bs 2buf x 2kk x [128][32] (32 KiB).
// Loads/thread/K-tile: A 2+2, B 1+1 = 6. Stage map P1:(t+1,A,k1) P2:(t+1,B,k1)
// P3:(t+2,A,k0) P4:(t+2,B,k0)+vmcnt(3) -> t+1 resident, t+2's 3 in flight.
// ---------------------------------------------------------------------------
__device__ __forceinline__ void mma256x128(
    const ushort* __restrict__ A, int lda, int abase,
    const ushort* __restrict__ B, int ldb, int bbase,
    int NT, ushort* As, ushort* Bs, f32x4 (&acc)[8][2])
{
    const int tid  = threadIdx.x;
    const int lane = tid & 63, w = tid >> 6;
    const int wr = w >> 2, wc = w & 3;
    const int lrow = lane & 15, kgrp = lane >> 4;
    const int srr = lane >> 2;
    const int scc = (lane & 3) * 8;

    auto stageA = [&](int t, int kk) {
        ushort* slot = As + (size_t)((t & 1) * 2 + kk) * 8192;
#pragma unroll
        for (int i = 0; i < 2; ++i) {
            const int r = (w * 2 + i) * 16 + srr;
            async16(&A[(size_t)(abase + r) * lda + t * 64 + kk * 32 + scc],
                    slot + (w * 2 + i) * 512);
        }
    };
    auto stageB = [&](int t, int kk) {
        ushort* slot = Bs + (size_t)((t & 1) * 2 + kk) * 4096;
        const int r = w * 16 + srr;
        async16(&B[(size_t)(bbase + r) * ldb + t * 64 + kk * 32 + scc],
                slot + w * 512);
    };

#pragma unroll
    for (int m = 0; m < 8; ++m)
#pragma unroll
        for (int n = 0; n < 2; ++n) acc[m][n] = (f32x4){0.f, 0.f, 0.f, 0.f};

    stageA(0, 0); stageB(0, 0); stageA(0, 1); stageB(0, 1);
    if (NT > 1) {
        stageA(1, 0); stageB(1, 0);
        asm volatile("s_waitcnt vmcnt(3)" ::: "memory");
    } else {
        asm volatile("s_waitcnt vmcnt(0)" ::: "memory");
    }
    SCHED();
    SBAR();
    SCHED();

    for (int t = 0; t < NT; ++t) {
        ushort* Ab = As + (size_t)(t & 1) * 16384;
        ushort* Bb = Bs + (size_t)(t & 1) * 8192;
        bf16x8 af[8], bfr;

        // ---- P1: (kk0, n0) ----
#pragma unroll
        for (int m = 0; m < 8; ++m)
            af[m] = *(const bf16x8*)&Ab[(wr * 128 + m * 16 + lrow) * 32 + kgrp * 8];
        bfr = *(const bf16x8*)&Bb[(wc * 32 + lrow) * 32 + kgrp * 8];
        if (t + 1 < NT) stageA(t + 1, 1);
        SBAR(); SCHED();
        __builtin_amdgcn_s_setprio(1);
#pragma unroll
        for (int m = 0; m < 8; ++m) acc[m][0] = MFMA16(af[m], bfr, acc[m][0]);
        __builtin_amdgcn_s_setprio(0);
        SBAR(); SCHED();

        // ---- P2: (kk0, n1) ----
        bfr = *(const bf16x8*)&Bb[(wc * 32 + 16 + lrow) * 32 + kgrp * 8];
        if (t + 1 < NT) stageB(t + 1, 1);
        SBAR(); SCHED();
        __builtin_amdgcn_s_setprio(1);
#pragma unroll
        for (int m = 0; m < 8; ++m) acc[m][1] = MFMA16(af[m], bfr, acc[m][1]);
        __builtin_amdgcn_s_setprio(0);
        SBAR(); SCHED();

        // ---- P3: (kk1, n0) ----
#pragma unroll
        for (int m = 0; m < 8; ++m)
            af[m] = *(const bf16x8*)&Ab[8192 + (wr * 128 + m * 16 + lrow) * 32 + kgrp * 8];
        bfr = *(const bf16x8*)&Bb[4096 + (wc * 32 + lrow) * 32 + kgrp * 8];
        if (t + 2 < NT) stageA(t + 2, 0);
        SBAR(); SCHED();
        __builtin_amdgcn_s_setprio(1);
#pragma unroll
        for (int m = 0; m < 8; ++m) acc[m][0] = MFMA16(af[m], bfr, acc[m][0]);
        __builtin_amdgcn_s_setprio(0);
        SBAR(); SCHED();

        // ---- P4: (kk1, n1) ----
        bfr = *(const bf16x8*)&Bb[4096 + (wc * 32 + 16 + lrow) * 32 + kgrp * 8];
        if (t + 2 < NT) {
            stageB(t + 2, 0);
            asm volatile("s_waitcnt vmcnt(3)" ::: "memory");
        } else if (t + 1 < NT) {
            asm volatile("s_waitcnt vmcnt(0)" ::: "memory");
        }
        SCHED();
        SBAR(); SCHED();
        __builtin_amdgcn_s_setprio(1);
#pragma unroll
        for (int m = 0; m < 8; ++m) acc[m][1] = MFMA16(af[m], bfr, acc[m][1]);
        __builtin_amdgcn_s_setprio(0);
        SBAR(); SCHED();
    }
}

// ---------------------------------------------------------------------------
// Kernel 1: Mtr[f][d] = (sum_e Wkt[f][e] * Wqt[d][e]) / 32  (scale folded).
// ---------------------------------------------------------------------------
__global__ __launch_bounds__(256) void m_gemm(
    const ushort* __restrict__ Wkt, const ushort* __restrict__ Wqt,
    ushort* __restrict__ Mtr)
{
    __shared__ ushort As[128 * 64];
    __shared__ ushort Bs[128 * 64];
    const int fbase = blockIdx.x * 128;
    const int dbase = blockIdx.y * 128;

    f32x4 acc[4][4];
    mma_tile(Wkt, 1024, fbase, Wqt, 1024, dbase, 16, As, Bs, acc);

    const int lane = threadIdx.x & 63, wid = threadIdx.x >> 6;
    const int wr = wid >> 1, wc = wid & 1;
    const int lrow = lane & 15, kgrp = lane >> 4;
#pragma unroll
    for (int m = 0; m < 4; ++m)
#pragma unroll
        for (int n = 0; n < 4; ++n)
#pragma unroll
            for (int r = 0; r < 4; ++r) {
                const int gf = fbase + wr * 64 + m * 16 + kgrp * 4 + r;
                const int gd = dbase + wc * 64 + n * 16 + lrow;
                Mtr[(size_t)gf * 1024 + gd] = f2bf(acc[m][n][r] * 0.03125f);
            }
}

// ---------------------------------------------------------------------------
// Kernel 2: 8-phase. z=0: T = xb @ Mtr^T -> Tb row-major. z=1: V -> Vt transposed.
// ---------------------------------------------------------------------------
__global__ __launch_bounds__(512, 2) void tv_gemm8(
    const ushort* __restrict__ xb, const ushort* __restrict__ Mtr,
    const ushort* __restrict__ Wvb,
    ushort* __restrict__ Tb, ushort* __restrict__ Vt)
{
    __shared__ ushort As[2 * 2 * 8192];
    __shared__ ushort Bs[2 * 2 * 8192];

    const int z = blockIdx.z;
    const ushort* Bmat = z ? Wvb : Mtr;
    const int mbase = blockIdx.x * 256;
    const int nbase = blockIdx.y * 256;

    f32x4 acc[8][4];
    mma256(xb, 1024, mbase, Bmat, 1024, nbase, 16, As, Bs, acc);

    const int lane = threadIdx.x & 63, w = threadIdx.x >> 6;
    const int wr = w >> 2, wc = w & 3;
    const int lrow = lane & 15, kgrp = lane >> 4;

    if (z == 1) {
        const int b  = mbase >> 11;
        const int s0 = mbase & 2047;
        ushort* VtB = Vt + (size_t)b * 1024 * 2048;
#pragma unroll
        for (int m = 0; m < 8; ++m)
#pragma unroll
            for (int n = 0; n < 4; ++n) {
                u16x4 pk;
#pragma unroll
                for (int r = 0; r < 4; ++r) pk[r] = f2bf(acc[m][n][r]);
                const int d = nbase + wc * 64 + n * 16 + lrow;
                const int s = s0 + wr * 128 + m * 16 + kgrp * 4;
                *(u16x4*)&VtB[(size_t)d * 2048 + s] = pk;
            }
    } else {
#pragma unroll
        for (int m = 0; m < 8; ++m)
#pragma unroll
            for (int n = 0; n < 4; ++n)
#pragma unroll
                for (int r = 0; r < 4; ++r) {
                    const int gr = mbase + wr * 128 + m * 16 + kgrp * 4 + r;
                    const int gc = nbase + wc * 64 + n * 16 + lrow;
                    Tb[(size_t)gr * 1024 + gc] = f2bf(acc[m][n][r]);
                }
    }
}

// ---------------------------------------------------------------------------
// Kernel 3: 8-phase scores S = T @ x^T (scale already in T), lower-tri 256-tiles.
// ---------------------------------------------------------------------------
__global__ __launch_bounds__(512, 2) void scores_gemm8(
    const ushort* __restrict__ Tb, const ushort* __restrict__ xb,
    ushort* __restrict__ Sall)
{
    __shared__ ushort As[2 * 2 * 8192];
    __shared__ ushort Bs[2 * 2 * 8192];

    ushort* S = Sall + (size_t)blockIdx.y * 2048 * 2048;
    const int rb = blockIdx.y * 2048;

    int t = blockIdx.x;
    int it = (int)((sqrtf(8.0f * (float)t + 1.0f) - 1.0f) * 0.5f);
    while ((it + 1) * (it + 2) / 2 <= t) ++it;
    while (it * (it + 1) / 2 > t) --it;
    const int jt = t - it * (it + 1) / 2;
    const int ibase = it * 256, jbase = jt * 256;

    f32x4 acc[8][4];
    mma256(Tb, 1024, rb + ibase, xb, 1024, rb + jbase, 16, As, Bs, acc);

    const int lane = threadIdx.x & 63, w = threadIdx.x >> 6;
    const int wr = w >> 2, wc = w & 3;
    const int lrow = lane & 15, kgrp = lane >> 4;
#pragma unroll
    for (int m = 0; m < 8; ++m)
#pragma unroll
        for (int n = 0; n < 4; ++n)
#pragma unroll
            for (int r = 0; r < 4; ++r) {
                const int gi = ibase + wr * 128 + m * 16 + kgrp * 4 + r;
                const int gj = jbase + wc * 64 + n * 16 + lrow;
                S[(size_t)gi * 2048 + gj] = f2bf(acc[m][n][r]);
            }
}

// ---------------------------------------------------------------------------
// Kernel 4: causal row softmax in place on bf16 S. One block per row.
// Stores zeros above the diagonal (incl. tiles scores never wrote).
// ---------------------------------------------------------------------------
__global__ __launch_bounds__(256) void softmax_rows(ushort* __restrict__ Sall)
{
    ushort* S = Sall + (size_t)blockIdx.y * 2048 * 2048;
    const int i   = blockIdx.x;
    const int tid = threadIdx.x;
    const int j0  = tid * 8;

    union { uint4 v; ushort u[8]; } pk;
    const bool anyvalid = (j0 <= i);
    if (anyvalid) pk.v = *(const uint4*)&S[(size_t)i * 2048 + j0];

    float f[8];
    float mx = -INFINITY;
#pragma unroll
    for (int e = 0; e < 8; ++e) {
        float v = (anyvalid && (j0 + e <= i)) ? bf2f(pk.u[e]) : -INFINITY;
        f[e] = v;
        mx = fmaxf(mx, v);
    }
#pragma unroll
    for (int off = 1; off < 64; off <<= 1) mx = fmaxf(mx, __shfl_xor(mx, off));
    __shared__ float redm[4];
    if ((tid & 63) == 0) redm[tid >> 6] = mx;
    __syncthreads();
    mx = fmaxf(fmaxf(redm[0], redm[1]), fmaxf(redm[2], redm[3]));

    float s = 0.f;
#pragma unroll
    for (int e = 0; e < 8; ++e) {
        float p = __expf(f[e] - mx);
        f[e] = p;
        s += p;
    }
#pragma unroll
    for (int off = 1; off < 64; off <<= 1) s += __shfl_xor(s, off);
    __shared__ float reds[4];
    if ((tid & 63) == 0) reds[tid >> 6] = s;
    __syncthreads();
    s = reds[0] + reds[1] + reds[2] + reds[3];

    const float inv = 1.0f / s;
#pragma unroll
    for (int e = 0; e < 8; ++e) pk.u[e] = f2bf(f[e] * inv);
    *(uint4*)&S[(size_t)i * 2048 + j0] = pk.v;
}

// ---------------------------------------------------------------------------
// Kernel 5: 8-phase O = P @ V, BM=256 x BN=128, K truncated at diagonal.
// grid (8 it, 8 nc, 4 b) = 256 blocks, heavy-first. fp32 out.
// ---------------------------------------------------------------------------
__global__ __launch_bounds__(512, 2) void pv_gemm8(
    const ushort* __restrict__ Pall, const ushort* __restrict__ Vtall,
    float* __restrict__ Oall)
{
    __shared__ ushort As[2 * 2 * 8192];   // 64 KiB
    __shared__ ushort Bs[2 * 2 * 4096];   // 32 KiB

    const ushort* P  = Pall  + (size_t)blockIdx.z * 2048 * 2048;
    const ushort* Vt = Vtall + (size_t)blockIdx.z * 1024 * 2048;
    float*        O  = Oall  + (size_t)blockIdx.z * 2048 * 1024;

    const int it = 7 - blockIdx.x;
    const int ibase = it * 256;
    const int nbase = blockIdx.y * 128;
    const int NT = 4 * (it + 1);

    f32x4 acc[8][2];
    mma256x128(P, 2048, ibase, Vt, 2048, nbase, NT, As, Bs, acc);

    const int lane = threadIdx.x & 63, w = threadIdx.x >> 6;
    const int wr = w >> 2, wc = w & 3;
    const int lrow = lane & 15, kgrp = lane >> 4;
#pragma unroll
    for (int m = 0; m < 8; ++m)
#pragma unroll
        for (int n = 0; n < 2; ++n)
#pragma unroll
            for (int r = 0; r < 4; ++r) {
                const int gi = ibase + wr * 128 + m * 16 + kgrp * 4 + r;
                const int gc = nbase + wc * 32 + n * 16 + lrow;
                O[(size_t)gi * 1024 + gc] = acc[m][n][r];
            }
}

// ---------------------------------------------------------------------------
extern "C" void kernel_launch(void* const* d_in, const int* in_sizes, int n_in,
                              void* d_out, int out_size, void* d_ws, size_t ws_size,
                              hipStream_t stream)
{
    (void)in_sizes; (void)n_in; (void)out_size; (void)ws_size;
    const float* x  = (const float*)d_in[0];
    const float* Wk = (const float*)d_in[1];
    const float* Wq = (const float*)d_in[2];
    const float* Wv = (const float*)d_in[3];
    float* out = (float*)d_out;

    const size_t M1 = (size_t)1024 * 1024;
    ushort* ws  = (ushort*)d_ws;
    ushort* xb  = ws;                      // 8M elems
    ushort* Tb  = xb  + 8 * M1;            // 8M
    ushort* Vt  = Tb  + 8 * M1;            // 8M (4 x [1024][2048])
    ushort* Sb  = Vt  + 8 * M1;            // 16M (4 x [2048][2048])
    ushort* Wkt = Sb  + 16 * M1;           // 1M
    ushort* Wqt = Wkt + M1;                // 1M
    ushort* Wvb = Wqt + M1;                // 1M
    ushort* Mtr = Wvb + M1;                // 1M

    // 0b) transpose-convert Wk, Wq
    cvt_transpose<<<dim3(32, 32, 2), dim3(32, 8), 0, stream>>>(Wk, Wq, Wkt, Wqt);
    // 0a) straight-convert x, Wv
    cvt_bf16<<<4608, 256, 0, stream>>>(x, Wv, xb, Wvb);
    // 1) M = (Wq^T Wk)/32 stored transposed
    m_gemm<<<dim3(8, 8), 256, 0, stream>>>(Wkt, Wqt, Mtr);
    // 2) T = x@M (z=0), V^T (z=1); 256 blocks = 1/CU
    tv_gemm8<<<dim3(32, 4, 2), 512, 0, stream>>>(xb, Mtr, Wvb, Tb, Vt);
    // 3) scores, lower-triangular 256-tiles
    scores_gemm8<<<dim3(36, 4), 512, 0, stream>>>(Tb, xb, Sb);
    // 4) softmax in place
    softmax_rows<<<dim3(2048, 4), 256, 0, stream>>>(Sb);
    // 5) O = P @ V, 8-phase 256x128
    pv_gemm8<<<dim3(8, 8, 4), 512, 0, stream>>>(Sb, Vt, out);
}

// Round 6
// 176.356 us; speedup vs baseline: 1.0264x; 1.0264x over previous
//
#include <hip/hip_runtime.h>

typedef __attribute__((ext_vector_type(8))) short bf16x8;
typedef __attribute__((ext_vector_type(4))) float f32x4;
typedef __attribute__((ext_vector_type(4))) unsigned short u16x4;
typedef __attribute__((ext_vector_type(8))) unsigned short u16x8;

#define MFMA16(a, b, c) __builtin_amdgcn_mfma_f32_16x16x32_bf16((a), (b), (c), 0, 0, 0)

__device__ __forceinline__ ushort f2bf(float f) {
    unsigned u = __float_as_uint(f);
    unsigned r = (u + 0x7FFFu + ((u >> 16) & 1u)) >> 16;
    return (ushort)r;
}
__device__ __forceinline__ float bf2f(ushort s) {
    return __uint_as_float(((unsigned)s) << 16);
}

// async global->LDS, 16B per lane. LDS dest is wave-uniform base + lane*16.
__device__ __forceinline__ void async16(const ushort* g, ushort* l) {
    __builtin_amdgcn_global_load_lds(
        (const __attribute__((address_space(1))) unsigned*)g,
        (__attribute__((address_space(3))) unsigned*)l, 16, 0, 0);
}

#define SBAR()  __builtin_amdgcn_s_barrier()
#define SCHED() __builtin_amdgcn_sched_barrier(0)

// ---------------------------------------------------------------------------
// Kernel 0: fused conversions.
// blocks [0,4608): straight fp32->bf16 of x and Wv.
// blocks [4608,6656): 32x32 transpose-convert of Wk (z=0) and Wq (z=1).
// ---------------------------------------------------------------------------
__global__ __launch_bounds__(256) void cvt_all(
    const float* __restrict__ x,  const float* __restrict__ wk,
    const float* __restrict__ wq, const float* __restrict__ wv,
    ushort* __restrict__ xb,  ushort* __restrict__ wvb,
    ushort* __restrict__ wkt, ushort* __restrict__ wqt)
{
    __shared__ float t[32][33];
    int bx = blockIdx.x;
    if (bx < 4608) {
        const size_t XN = (size_t)8192 * 1024;
        size_t idx = ((size_t)bx * 256 + threadIdx.x) * 8;
        const float* s;
        ushort* d;
        if (idx < XN) { s = x + idx; d = xb + idx; }
        else          { s = wv + (idx - XN); d = wvb + (idx - XN); }
        float4 a = *(const float4*)s;
        float4 b = *(const float4*)(s + 4);
        u16x8 p;
        p[0] = f2bf(a.x); p[1] = f2bf(a.y); p[2] = f2bf(a.z); p[3] = f2bf(a.w);
        p[4] = f2bf(b.x); p[5] = f2bf(b.y); p[6] = f2bf(b.z); p[7] = f2bf(b.w);
        *(u16x8*)d = p;
    } else {
        bx -= 4608;
        const int z  = bx >> 10;
        const int tb = bx & 1023;
        const int e0 = (tb & 31) * 32, d0 = (tb >> 5) * 32;
        const float* src = z ? wq : wk;
        ushort*      dst = z ? wqt : wkt;
        const int tx = threadIdx.x & 31, ty = threadIdx.x >> 5;
#pragma unroll
        for (int r = 0; r < 4; ++r)
            t[ty + 8 * r][tx] = src[(size_t)(e0 + ty + 8 * r) * 1024 + d0 + tx];
        __syncthreads();
#pragma unroll
        for (int r = 0; r < 4; ++r)
            dst[(size_t)(d0 + ty + 8 * r) * 1024 + e0 + tx] = f2bf(t[tx][ty + 8 * r]);
    }
}

// ---------------------------------------------------------------------------
// 2-phase 128x128 core (kept for m_gemm). 256 threads.
// ---------------------------------------------------------------------------
__device__ __forceinline__ void mma_tile(
    const ushort* __restrict__ A, int lda, int abase,
    const ushort* __restrict__ B, int ldb, int bbase,
    int ktiles,
    ushort* As, ushort* Bs, f32x4 (&acc)[4][4])
{
    const int tid  = threadIdx.x;
    const int lane = tid & 63, wid = tid >> 6;
    const int wr = wid >> 1, wc = wid & 1;
    const int lrow = lane & 15, kgrp = lane >> 4;
    const int ci = lane >> 3;
    const int cc = (lane & 7) * 8;

#pragma unroll
    for (int m = 0; m < 4; ++m)
#pragma unroll
        for (int n = 0; n < 4; ++n) acc[m][n] = (f32x4){0.f, 0.f, 0.f, 0.f};

    for (int kt = 0; kt < ktiles; ++kt) {
        const int k0 = kt * 64;
#pragma unroll
        for (int i = 0; i < 4; ++i) {
            const int r = (wid * 4 + i) * 8 + ci;
            async16(&A[(size_t)(abase + r) * lda + k0 + cc], &As[(wid * 4 + i) * 512]);
            async16(&B[(size_t)(bbase + r) * ldb + k0 + cc], &Bs[(wid * 4 + i) * 512]);
        }
        __syncthreads();
#pragma unroll
        for (int kk = 0; kk < 2; ++kk) {
            bf16x8 af[4], bfr[4];
#pragma unroll
            for (int m = 0; m < 4; ++m)
                af[m] = *(const bf16x8*)&As[(wr * 64 + m * 16 + lrow) * 64 + kk * 32 + kgrp * 8];
#pragma unroll
            for (int n = 0; n < 4; ++n)
                bfr[n] = *(const bf16x8*)&Bs[(wc * 64 + n * 16 + lrow) * 64 + kk * 32 + kgrp * 8];
#pragma unroll
            for (int m = 0; m < 4; ++m)
#pragma unroll
                for (int n = 0; n < 4; ++n)
                    acc[m][n] = MFMA16(af[m], bfr[n], acc[m][n]);
        }
        __syncthreads();
    }
}

// ---------------------------------------------------------------------------
// 8-phase 256x256 core (tv, scores). 512 threads = 8 waves (2x4).
// ---------------------------------------------------------------------------
__device__ __forceinline__ void mma256(
    const ushort* __restrict__ A, int lda, int abase,
    const ushort* __restrict__ B, int ldb, int bbase,
    int NT, ushort* As, ushort* Bs, f32x4 (&acc)[8][4])
{
    const int tid  = threadIdx.x;
    const int lane = tid & 63, w = tid >> 6;
    const int wr = w >> 2, wc = w & 3;
    const int lrow = lane & 15, kgrp = lane >> 4;
    const int srr = lane >> 2;
    const int scc = (lane & 3) * 8;

    auto stage = [&](int t, int isB, int kk) {
        const ushort* src = isB ? B : A;
        const int ld = isB ? ldb : lda;
        const int rb = isB ? bbase : abase;
        ushort* slot = (isB ? Bs : As) + (size_t)(((t & 1) * 2 + kk)) * 8192;
#pragma unroll
        for (int i = 0; i < 2; ++i) {
            const int r = (w * 2 + i) * 16 + srr;
            async16(&src[(size_t)(rb + r) * ld + t * 64 + kk * 32 + scc],
                    slot + (w * 2 + i) * 512);
        }
    };

#pragma unroll
    for (int m = 0; m < 8; ++m)
#pragma unroll
        for (int n = 0; n < 4; ++n) acc[m][n] = (f32x4){0.f, 0.f, 0.f, 0.f};

    stage(0, 0, 0); stage(0, 1, 0); stage(0, 0, 1); stage(0, 1, 1);
    if (NT > 1) {
        stage(1, 0, 0); stage(1, 1, 0);
        asm volatile("s_waitcnt vmcnt(4)" ::: "memory");
    } else {
        asm volatile("s_waitcnt vmcnt(0)" ::: "memory");
    }
    SCHED();
    SBAR();
    SCHED();

    for (int t = 0; t < NT; ++t) {
        ushort* Ab = As + (size_t)(t & 1) * 2 * 8192;
        ushort* Bb = Bs + (size_t)(t & 1) * 2 * 8192;
        bf16x8 af[8], bfr[2];

        // ---- P1: (kk0, n0-1) ----
#pragma unroll
        for (int m = 0; m < 8; ++m)
            af[m] = *(const bf16x8*)&Ab[(wr * 128 + m * 16 + lrow) * 32 + kgrp * 8];
#pragma unroll
        for (int n = 0; n < 2; ++n)
            bfr[n] = *(const bf16x8*)&Bb[(wc * 64 + n * 16 + lrow) * 32 + kgrp * 8];
        if (t + 1 < NT) stage(t + 1, 0, 1);
        SBAR(); SCHED();
        __builtin_amdgcn_s_setprio(1);
#pragma unroll
        for (int m = 0; m < 8; ++m) {
            acc[m][0] = MFMA16(af[m], bfr[0], acc[m][0]);
            acc[m][1] = MFMA16(af[m], bfr[1], acc[m][1]);
        }
        __builtin_amdgcn_s_setprio(0);
        SBAR(); SCHED();

        // ---- P2: (kk0, n2-3) ----
#pragma unroll
        for (int n = 0; n < 2; ++n)
            bfr[n] = *(const bf16x8*)&Bb[(wc * 64 + (2 + n) * 16 + lrow) * 32 + kgrp * 8];
        if (t + 1 < NT) stage(t + 1, 1, 1);
        SBAR(); SCHED();
        __builtin_amdgcn_s_setprio(1);
#pragma unroll
        for (int m = 0; m < 8; ++m) {
            acc[m][2] = MFMA16(af[m], bfr[0], acc[m][2]);
            acc[m][3] = MFMA16(af[m], bfr[1], acc[m][3]);
        }
        __builtin_amdgcn_s_setprio(0);
        SBAR(); SCHED();

        // ---- P3: (kk1, n0-1) ----
#pragma unroll
        for (int m = 0; m < 8; ++m)
            af[m] = *(const bf16x8*)&Ab[8192 + (wr * 128 + m * 16 + lrow) * 32 + kgrp * 8];
#pragma unroll
        for (int n = 0; n < 2; ++n)
            bfr[n] = *(const bf16x8*)&Bb[8192 + (wc * 64 + n * 16 + lrow) * 32 + kgrp * 8];
        if (t + 2 < NT) stage(t + 2, 0, 0);
        SBAR(); SCHED();
        __builtin_amdgcn_s_setprio(1);
#pragma unroll
        for (int m = 0; m < 8; ++m) {
            acc[m][0] = MFMA16(af[m], bfr[0], acc[m][0]);
            acc[m][1] = MFMA16(af[m], bfr[1], acc[m][1]);
        }
        __builtin_amdgcn_s_setprio(0);
        SBAR(); SCHED();

        // ---- P4: (kk1, n2-3) ----
#pragma unroll
        for (int n = 0; n < 2; ++n)
            bfr[n] = *(const bf16x8*)&Bb[8192 + (wc * 64 + (2 + n) * 16 + lrow) * 32 + kgrp * 8];
        if (t + 2 < NT) {
            stage(t + 2, 1, 0);
            asm volatile("s_waitcnt vmcnt(4)" ::: "memory");
        } else if (t + 1 < NT) {
            asm volatile("s_waitcnt vmcnt(0)" ::: "memory");
        }
        SCHED();
        SBAR(); SCHED();
        __builtin_amdgcn_s_setprio(1);
#pragma unroll
        for (int m = 0; m < 8; ++m) {
            acc[m][2] = MFMA16(af[m], bfr[0], acc[m][2]);
            acc[m][3] = MFMA16(af[m], bfr[1], acc[m][3]);
        }
        __builtin_amdgcn_s_setprio(0);
        SBAR(); SCHED();
    }
}

// ---------------------------------------------------------------------------
// FAT single-phase 256x128 core for PV. 512 threads = 8 waves (2x4 of 128x32).
// Per K-tile: ONE cluster of 32 MFMA/wave, 2 barriers, counted vmcnt(6),
// 2-tile-deep prefetch (6 loads/thread/K-tile).
// ---------------------------------------------------------------------------
__device__ __forceinline__ void mma256x128_fat(
    const ushort* __restrict__ A, int lda, int abase,
    const ushort* __restrict__ B, int ldb, int bbase,
    int NT, ushort* As, ushort* Bs, f32x4 (&acc)[8][2])
{
    const int tid  = threadIdx.x;
    const int lane = tid & 63, w = tid >> 6;
    const int wr = w >> 2, wc = w & 3;
    const int lrow = lane & 15, kgrp = lane >> 4;
    const int srr = lane >> 2;
    const int scc = (lane & 3) * 8;

    auto stage6 = [&](int t) {
#pragma unroll
        for (int kk = 0; kk < 2; ++kk) {
            ushort* slotA = As + (size_t)((t & 1) * 2 + kk) * 8192;
#pragma unroll
            for (int i = 0; i < 2; ++i) {
                const int r = (w * 2 + i) * 16 + srr;
                async16(&A[(size_t)(abase + r) * lda + t * 64 + kk * 32 + scc],
                        slotA + (w * 2 + i) * 512);
            }
            ushort* slotB = Bs + (size_t)((t & 1) * 2 + kk) * 4096;
            const int rB = w * 16 + srr;
            async16(&B[(size_t)(bbase + rB) * ldb + t * 64 + kk * 32 + scc],
                    slotB + w * 512);
        }
    };

#pragma unroll
    for (int m = 0; m < 8; ++m)
#pragma unroll
        for (int n = 0; n < 2; ++n) acc[m][n] = (f32x4){0.f, 0.f, 0.f, 0.f};

    stage6(0);
    stage6(1);
    asm volatile("s_waitcnt vmcnt(6)" ::: "memory");   // tile 0 resident
    SCHED();
    SBAR(); SCHED();

    for (int t = 0; t < NT; ++t) {
        ushort* Ab = As + (size_t)(t & 1) * 16384;
        ushort* Bb = Bs + (size_t)(t & 1) * 8192;
        bf16x8 af[2][8], bq[2][2];
#pragma unroll
        for (int kk = 0; kk < 2; ++kk) {
#pragma unroll
            for (int m = 0; m < 8; ++m)
                af[kk][m] = *(const bf16x8*)&Ab[kk * 8192 + (wr * 128 + m * 16 + lrow) * 32 + kgrp * 8];
#pragma unroll
            for (int n = 0; n < 2; ++n)
                bq[kk][n] = *(const bf16x8*)&Bb[kk * 4096 + (wc * 32 + n * 16 + lrow) * 32 + kgrp * 8];
        }
        asm volatile("s_waitcnt lgkmcnt(0)" ::: "memory");
        SCHED();
        SBAR(); SCHED();               // buf[t&1] fully read -> released
        if (t + 2 < NT) {
            stage6(t + 2);
            asm volatile("s_waitcnt vmcnt(6)" ::: "memory");  // t+1 complete
        } else if (t + 1 < NT) {
            asm volatile("s_waitcnt vmcnt(0)" ::: "memory");
        }
        SCHED();
        SBAR(); SCHED();               // t+1 resident for all waves
        __builtin_amdgcn_s_setprio(1);
#pragma unroll
        for (int kk = 0; kk < 2; ++kk)
#pragma unroll
            for (int m = 0; m < 8; ++m) {
                acc[m][0] = MFMA16(af[kk][m], bq[kk][0], acc[m][0]);
                acc[m][1] = MFMA16(af[kk][m], bq[kk][1], acc[m][1]);
            }
        __builtin_amdgcn_s_setprio(0);
    }
}

// ---------------------------------------------------------------------------
// Kernel 1: Mtr[f][d] = (sum_e Wkt[f][e] * Wqt[d][e]) / 32  (scale folded).
// ---------------------------------------------------------------------------
__global__ __launch_bounds__(256) void m_gemm(
    const ushort* __restrict__ Wkt, const ushort* __restrict__ Wqt,
    ushort* __restrict__ Mtr)
{
    __shared__ ushort As[128 * 64];
    __shared__ ushort Bs[128 * 64];
    const int fbase = blockIdx.x * 128;
    const int dbase = blockIdx.y * 128;

    f32x4 acc[4][4];
    mma_tile(Wkt, 1024, fbase, Wqt, 1024, dbase, 16, As, Bs, acc);

    const int lane = threadIdx.x & 63, wid = threadIdx.x >> 6;
    const int wr = wid >> 1, wc = wid & 1;
    const int lrow = lane & 15, kgrp = lane >> 4;
#pragma unroll
    for (int m = 0; m < 4; ++m)
#pragma unroll
        for (int n = 0; n < 4; ++n)
#pragma unroll
            for (int r = 0; r < 4; ++r) {
                const int gf = fbase + wr * 64 + m * 16 + kgrp * 4 + r;
                const int gd = dbase + wc * 64 + n * 16 + lrow;
                Mtr[(size_t)gf * 1024 + gd] = f2bf(acc[m][n][r] * 0.03125f);
            }
}

// ---------------------------------------------------------------------------
// Kernel 2: 8-phase. z=0: T = xb @ Mtr^T -> Tb row-major. z=1: V -> Vt transposed.
// ---------------------------------------------------------------------------
__global__ __launch_bounds__(512, 2) void tv_gemm8(
    const ushort* __restrict__ xb, const ushort* __restrict__ Mtr,
    const ushort* __restrict__ Wvb,
    ushort* __restrict__ Tb, ushort* __restrict__ Vt)
{
    __shared__ ushort As[2 * 2 * 8192];
    __shared__ ushort Bs[2 * 2 * 8192];

    const int z = blockIdx.z;
    const ushort* Bmat = z ? Wvb : Mtr;
    const int mbase = blockIdx.x * 256;
    const int nbase = blockIdx.y * 256;

    f32x4 acc[8][4];
    mma256(xb, 1024, mbase, Bmat, 1024, nbase, 16, As, Bs, acc);

    const int lane = threadIdx.x & 63, w = threadIdx.x >> 6;
    const int wr = w >> 2, wc = w & 3;
    const int lrow = lane & 15, kgrp = lane >> 4;

    if (z == 1) {
        const int b  = mbase >> 11;
        const int s0 = mbase & 2047;
        ushort* VtB = Vt + (size_t)b * 1024 * 2048;
#pragma unroll
        for (int m = 0; m < 8; ++m)
#pragma unroll
            for (int n = 0; n < 4; ++n) {
                u16x4 pk;
#pragma unroll
                for (int r = 0; r < 4; ++r) pk[r] = f2bf(acc[m][n][r]);
                const int d = nbase + wc * 64 + n * 16 + lrow;
                const int s = s0 + wr * 128 + m * 16 + kgrp * 4;
                *(u16x4*)&VtB[(size_t)d * 2048 + s] = pk;
            }
    } else {
#pragma unroll
        for (int m = 0; m < 8; ++m)
#pragma unroll
            for (int n = 0; n < 4; ++n)
#pragma unroll
                for (int r = 0; r < 4; ++r) {
                    const int gr = mbase + wr * 128 + m * 16 + kgrp * 4 + r;
                    const int gc = nbase + wc * 64 + n * 16 + lrow;
                    Tb[(size_t)gr * 1024 + gc] = f2bf(acc[m][n][r]);
                }
    }
}

// ---------------------------------------------------------------------------
// Kernel 3: 8-phase scores S = T @ x^T (scale already in T), lower-tri 256-tiles.
// ---------------------------------------------------------------------------
__global__ __launch_bounds__(512, 2) void scores_gemm8(
    const ushort* __restrict__ Tb, const ushort* __restrict__ xb,
    ushort* __restrict__ Sall)
{
    __shared__ ushort As[2 * 2 * 8192];
    __shared__ ushort Bs[2 * 2 * 8192];

    ushort* S = Sall + (size_t)blockIdx.y * 2048 * 2048;
    const int rb = blockIdx.y * 2048;

    int t = blockIdx.x;
    int it = (int)((sqrtf(8.0f * (float)t + 1.0f) - 1.0f) * 0.5f);
    while ((it + 1) * (it + 2) / 2 <= t) ++it;
    while (it * (it + 1) / 2 > t) --it;
    const int jt = t - it * (it + 1) / 2;
    const int ibase = it * 256, jbase = jt * 256;

    f32x4 acc[8][4];
    mma256(Tb, 1024, rb + ibase, xb, 1024, rb + jbase, 16, As, Bs, acc);

    const int lane = threadIdx.x & 63, w = threadIdx.x >> 6;
    const int wr = w >> 2, wc = w & 3;
    const int lrow = lane & 15, kgrp = lane >> 4;
#pragma unroll
    for (int m = 0; m < 8; ++m)
#pragma unroll
        for (int n = 0; n < 4; ++n)
#pragma unroll
            for (int r = 0; r < 4; ++r) {
                const int gi = ibase + wr * 128 + m * 16 + kgrp * 4 + r;
                const int gj = jbase + wc * 64 + n * 16 + lrow;
                S[(size_t)gi * 2048 + gj] = f2bf(acc[m][n][r]);
            }
}

// ---------------------------------------------------------------------------
// Kernel 4: causal row softmax in place on bf16 S. One block per row.
// Writes only j < 256*((i>>8)+1) — exactly the range PV reads for this row.
// ---------------------------------------------------------------------------
__global__ __launch_bounds__(256) void softmax_rows(ushort* __restrict__ Sall)
{
    ushort* S = Sall + (size_t)blockIdx.y * 2048 * 2048;
    const int i   = blockIdx.x;
    const int tid = threadIdx.x;
    const int j0  = tid * 8;
    const int limit = ((i >> 8) + 1) * 256;

    union { uint4 v; ushort u[8]; } pk;
    const bool anyvalid = (j0 <= i);
    if (anyvalid) pk.v = *(const uint4*)&S[(size_t)i * 2048 + j0];

    float f[8];
    float mx = -INFINITY;
#pragma unroll
    for (int e = 0; e < 8; ++e) {
        float v = (anyvalid && (j0 + e <= i)) ? bf2f(pk.u[e]) : -INFINITY;
        f[e] = v;
        mx = fmaxf(mx, v);
    }
#pragma unroll
    for (int off = 1; off < 64; off <<= 1) mx = fmaxf(mx, __shfl_xor(mx, off));
    __shared__ float redm[4];
    if ((tid & 63) == 0) redm[tid >> 6] = mx;
    __syncthreads();
    mx = fmaxf(fmaxf(redm[0], redm[1]), fmaxf(redm[2], redm[3]));

    float s = 0.f;
#pragma unroll
    for (int e = 0; e < 8; ++e) {
        float p = __expf(f[e] - mx);
        f[e] = p;
        s += p;
    }
#pragma unroll
    for (int off = 1; off < 64; off <<= 1) s += __shfl_xor(s, off);
    __shared__ float reds[4];
    if ((tid & 63) == 0) reds[tid >> 6] = s;
    __syncthreads();
    s = reds[0] + reds[1] + reds[2] + reds[3];

    const float inv = 1.0f / s;
#pragma unroll
    for (int e = 0; e < 8; ++e) pk.u[e] = f2bf(f[e] * inv);
    if (j0 < limit) *(uint4*)&S[(size_t)i * 2048 + j0] = pk.v;
}

// ---------------------------------------------------------------------------
// Kernel 5: FAT single-phase O = P @ V, BM=256 x BN=128, K truncated at diag.
// grid (8 it, 8 nc, 4 b) = 256 blocks. fp32 out.
// ---------------------------------------------------------------------------
__global__ __launch_bounds__(512, 2) void pv_fat(
    const ushort* __restrict__ Pall, const ushort* __restrict__ Vtall,
    float* __restrict__ Oall)
{
    __shared__ ushort As[2 * 2 * 8192];   // 64 KiB
    __shared__ ushort Bs[2 * 2 * 4096];   // 32 KiB

    const ushort* P  = Pall  + (size_t)blockIdx.z * 2048 * 2048;
    const ushort* Vt = Vtall + (size_t)blockIdx.z * 1024 * 2048;
    float*        O  = Oall  + (size_t)blockIdx.z * 2048 * 1024;

    const int it = 7 - blockIdx.x;
    const int ibase = it * 256;
    const int nbase = blockIdx.y * 128;
    const int NT = 4 * (it + 1);

    f32x4 acc[8][2];
    mma256x128_fat(P, 2048, ibase, Vt, 2048, nbase, NT, As, Bs, acc);

    const int lane = threadIdx.x & 63, w = threadIdx.x >> 6;
    const int wr = w >> 2, wc = w & 3;
    const int lrow = lane & 15, kgrp = lane >> 4;
#pragma unroll
    for (int m = 0; m < 8; ++m)
#pragma unroll
        for (int n = 0; n < 2; ++n)
#pragma unroll
            for (int r = 0; r < 4; ++r) {
                const int gi = ibase + wr * 128 + m * 16 + kgrp * 4 + r;
                const int gc = nbase + wc * 32 + n * 16 + lrow;
                O[(size_t)gi * 1024 + gc] = acc[m][n][r];
            }
}

// ---------------------------------------------------------------------------
extern "C" void kernel_launch(void* const* d_in, const int* in_sizes, int n_in,
                              void* d_out, int out_size, void* d_ws, size_t ws_size,
                              hipStream_t stream)
{
    (void)in_sizes; (void)n_in; (void)out_size; (void)ws_size;
    const float* x  = (const float*)d_in[0];
    const float* Wk = (const float*)d_in[1];
    const float* Wq = (const float*)d_in[2];
    const float* Wv = (const float*)d_in[3];
    float* out = (float*)d_out;

    const size_t M1 = (size_t)1024 * 1024;
    ushort* ws  = (ushort*)d_ws;
    ushort* xb  = ws;                      // 8M elems
    ushort* Tb  = xb  + 8 * M1;            // 8M
    ushort* Vt  = Tb  + 8 * M1;            // 8M (4 x [1024][2048])
    ushort* Sb  = Vt  + 8 * M1;            // 16M (4 x [2048][2048])
    ushort* Wkt = Sb  + 16 * M1;           // 1M
    ushort* Wqt = Wkt + M1;                // 1M
    ushort* Wvb = Wqt + M1;                // 1M
    ushort* Mtr = Wvb + M1;                // 1M

    // 0) fused conversions (x, Wv straight; Wk, Wq transposed)
    cvt_all<<<6656, 256, 0, stream>>>(x, Wk, Wq, Wv, xb, Wvb, Wkt, Wqt);
    // 1) M = (Wq^T Wk)/32 stored transposed
    m_gemm<<<dim3(8, 8), 256, 0, stream>>>(Wkt, Wqt, Mtr);
    // 2) T = x@M (z=0), V^T (z=1); 256 blocks = 1/CU
    tv_gemm8<<<dim3(32, 4, 2), 512, 0, stream>>>(xb, Mtr, Wvb, Tb, Vt);
    // 3) scores, lower-triangular 256-tiles
    scores_gemm8<<<dim3(36, 4), 512, 0, stream>>>(Tb, xb, Sb);
    // 4) softmax in place (stores trimmed to PV's read range)
    softmax_rows<<<dim3(2048, 4), 256, 0, stream>>>(Sb);
    // 5) O = P @ V, fat single-phase 256x128
    pv_fat<<<dim3(8, 8, 4), 512, 0, stream>>>(Sb, Vt, out);
}

// Round 7
// 156.756 us; speedup vs baseline: 1.1547x; 1.1250x over previous
//
#include <hip/hip_runtime.h>

typedef __attribute__((ext_vector_type(8))) short bf16x8;
typedef __attribute__((ext_vector_type(4))) float f32x4;
typedef __attribute__((ext_vector_type(4))) unsigned short u16x4;
typedef __attribute__((ext_vector_type(8))) unsigned short u16x8;

#define MFMA16(a, b, c) __builtin_amdgcn_mfma_f32_16x16x32_bf16((a), (b), (c), 0, 0, 0)

__device__ __forceinline__ ushort f2bf(float f) {
    unsigned u = __float_as_uint(f);
    unsigned r = (u + 0x7FFFu + ((u >> 16) & 1u)) >> 16;
    return (ushort)r;
}
__device__ __forceinline__ float bf2f(ushort s) {
    return __uint_as_float(((unsigned)s) << 16);
}

// async global->LDS, 16B per lane. LDS dest is wave-uniform base + lane*16.
__device__ __forceinline__ void async16(const ushort* g, ushort* l) {
    __builtin_amdgcn_global_load_lds(
        (const __attribute__((address_space(1))) unsigned*)g,
        (__attribute__((address_space(3))) unsigned*)l, 16, 0, 0);
}

#define SBAR()  __builtin_amdgcn_s_barrier()
#define SCHED() __builtin_amdgcn_sched_barrier(0)

// ---------------------------------------------------------------------------
// Kernel 0: fused conversions.
// blocks [0,4608): straight fp32->bf16 of x and Wv.
// blocks [4608,6656): 32x32 transpose-convert of Wk (z=0) and Wq (z=1).
// ---------------------------------------------------------------------------
__global__ __launch_bounds__(256) void cvt_all(
    const float* __restrict__ x,  const float* __restrict__ wk,
    const float* __restrict__ wq, const float* __restrict__ wv,
    ushort* __restrict__ xb,  ushort* __restrict__ wvb,
    ushort* __restrict__ wkt, ushort* __restrict__ wqt)
{
    __shared__ float t[32][33];
    int bx = blockIdx.x;
    if (bx < 4608) {
        const size_t XN = (size_t)8192 * 1024;
        size_t idx = ((size_t)bx * 256 + threadIdx.x) * 8;
        const float* s;
        ushort* d;
        if (idx < XN) { s = x + idx; d = xb + idx; }
        else          { s = wv + (idx - XN); d = wvb + (idx - XN); }
        float4 a = *(const float4*)s;
        float4 b = *(const float4*)(s + 4);
        u16x8 p;
        p[0] = f2bf(a.x); p[1] = f2bf(a.y); p[2] = f2bf(a.z); p[3] = f2bf(a.w);
        p[4] = f2bf(b.x); p[5] = f2bf(b.y); p[6] = f2bf(b.z); p[7] = f2bf(b.w);
        *(u16x8*)d = p;
    } else {
        bx -= 4608;
        const int z  = bx >> 10;
        const int tb = bx & 1023;
        const int e0 = (tb & 31) * 32, d0 = (tb >> 5) * 32;
        const float* src = z ? wq : wk;
        ushort*      dst = z ? wqt : wkt;
        const int tx = threadIdx.x & 31, ty = threadIdx.x >> 5;
#pragma unroll
        for (int r = 0; r < 4; ++r)
            t[ty + 8 * r][tx] = src[(size_t)(e0 + ty + 8 * r) * 1024 + d0 + tx];
        __syncthreads();
#pragma unroll
        for (int r = 0; r < 4; ++r)
            dst[(size_t)(d0 + ty + 8 * r) * 1024 + e0 + tx] = f2bf(t[tx][ty + 8 * r]);
    }
}

// ---------------------------------------------------------------------------
// 2-phase 128x128 core (kept for m_gemm). 256 threads.
// ---------------------------------------------------------------------------
__device__ __forceinline__ void mma_tile(
    const ushort* __restrict__ A, int lda, int abase,
    const ushort* __restrict__ B, int ldb, int bbase,
    int ktiles,
    ushort* As, ushort* Bs, f32x4 (&acc)[4][4])
{
    const int tid  = threadIdx.x;
    const int lane = tid & 63, wid = tid >> 6;
    const int wr = wid >> 1, wc = wid & 1;
    const int lrow = lane & 15, kgrp = lane >> 4;
    const int ci = lane >> 3;
    const int cc = (lane & 7) * 8;

#pragma unroll
    for (int m = 0; m < 4; ++m)
#pragma unroll
        for (int n = 0; n < 4; ++n) acc[m][n] = (f32x4){0.f, 0.f, 0.f, 0.f};

    for (int kt = 0; kt < ktiles; ++kt) {
        const int k0 = kt * 64;
#pragma unroll
        for (int i = 0; i < 4; ++i) {
            const int r = (wid * 4 + i) * 8 + ci;
            async16(&A[(size_t)(abase + r) * lda + k0 + cc], &As[(wid * 4 + i) * 512]);
            async16(&B[(size_t)(bbase + r) * ldb + k0 + cc], &Bs[(wid * 4 + i) * 512]);
        }
        __syncthreads();
#pragma unroll
        for (int kk = 0; kk < 2; ++kk) {
            bf16x8 af[4], bfr[4];
#pragma unroll
            for (int m = 0; m < 4; ++m)
                af[m] = *(const bf16x8*)&As[(wr * 64 + m * 16 + lrow) * 64 + kk * 32 + kgrp * 8];
#pragma unroll
            for (int n = 0; n < 4; ++n)
                bfr[n] = *(const bf16x8*)&Bs[(wc * 64 + n * 16 + lrow) * 64 + kk * 32 + kgrp * 8];
#pragma unroll
            for (int m = 0; m < 4; ++m)
#pragma unroll
                for (int n = 0; n < 4; ++n)
                    acc[m][n] = MFMA16(af[m], bfr[n], acc[m][n]);
        }
        __syncthreads();
    }
}

// ---------------------------------------------------------------------------
// 8-phase 256x256 core (tv, scores). 512 threads = 8 waves (2x4).
// ---------------------------------------------------------------------------
__device__ __forceinline__ void mma256(
    const ushort* __restrict__ A, int lda, int abase,
    const ushort* __restrict__ B, int ldb, int bbase,
    int NT, ushort* As, ushort* Bs, f32x4 (&acc)[8][4])
{
    const int tid  = threadIdx.x;
    const int lane = tid & 63, w = tid >> 6;
    const int wr = w >> 2, wc = w & 3;
    const int lrow = lane & 15, kgrp = lane >> 4;
    const int srr = lane >> 2;
    const int scc = (lane & 3) * 8;

    auto stage = [&](int t, int isB, int kk) {
        const ushort* src = isB ? B : A;
        const int ld = isB ? ldb : lda;
        const int rb = isB ? bbase : abase;
        ushort* slot = (isB ? Bs : As) + (size_t)(((t & 1) * 2 + kk)) * 8192;
#pragma unroll
        for (int i = 0; i < 2; ++i) {
            const int r = (w * 2 + i) * 16 + srr;
            async16(&src[(size_t)(rb + r) * ld + t * 64 + kk * 32 + scc],
                    slot + (w * 2 + i) * 512);
        }
    };

#pragma unroll
    for (int m = 0; m < 8; ++m)
#pragma unroll
        for (int n = 0; n < 4; ++n) acc[m][n] = (f32x4){0.f, 0.f, 0.f, 0.f};

    stage(0, 0, 0); stage(0, 1, 0); stage(0, 0, 1); stage(0, 1, 1);
    if (NT > 1) {
        stage(1, 0, 0); stage(1, 1, 0);
        asm volatile("s_waitcnt vmcnt(4)" ::: "memory");
    } else {
        asm volatile("s_waitcnt vmcnt(0)" ::: "memory");
    }
    SCHED();
    SBAR();
    SCHED();

    for (int t = 0; t < NT; ++t) {
        ushort* Ab = As + (size_t)(t & 1) * 2 * 8192;
        ushort* Bb = Bs + (size_t)(t & 1) * 2 * 8192;
        bf16x8 af[8], bfr[2];

        // ---- P1: (kk0, n0-1) ----
#pragma unroll
        for (int m = 0; m < 8; ++m)
            af[m] = *(const bf16x8*)&Ab[(wr * 128 + m * 16 + lrow) * 32 + kgrp * 8];
#pragma unroll
        for (int n = 0; n < 2; ++n)
            bfr[n] = *(const bf16x8*)&Bb[(wc * 64 + n * 16 + lrow) * 32 + kgrp * 8];
        if (t + 1 < NT) stage(t + 1, 0, 1);
        SBAR(); SCHED();
        __builtin_amdgcn_s_setprio(1);
#pragma unroll
        for (int m = 0; m < 8; ++m) {
            acc[m][0] = MFMA16(af[m], bfr[0], acc[m][0]);
            acc[m][1] = MFMA16(af[m], bfr[1], acc[m][1]);
        }
        __builtin_amdgcn_s_setprio(0);
        SBAR(); SCHED();

        // ---- P2: (kk0, n2-3) ----
#pragma unroll
        for (int n = 0; n < 2; ++n)
            bfr[n] = *(const bf16x8*)&Bb[(wc * 64 + (2 + n) * 16 + lrow) * 32 + kgrp * 8];
        if (t + 1 < NT) stage(t + 1, 1, 1);
        SBAR(); SCHED();
        __builtin_amdgcn_s_setprio(1);
#pragma unroll
        for (int m = 0; m < 8; ++m) {
            acc[m][2] = MFMA16(af[m], bfr[0], acc[m][2]);
            acc[m][3] = MFMA16(af[m], bfr[1], acc[m][3]);
        }
        __builtin_amdgcn_s_setprio(0);
        SBAR(); SCHED();

        // ---- P3: (kk1, n0-1) ----
#pragma unroll
        for (int m = 0; m < 8; ++m)
            af[m] = *(const bf16x8*)&Ab[8192 + (wr * 128 + m * 16 + lrow) * 32 + kgrp * 8];
#pragma unroll
        for (int n = 0; n < 2; ++n)
            bfr[n] = *(const bf16x8*)&Bb[8192 + (wc * 64 + n * 16 + lrow) * 32 + kgrp * 8];
        if (t + 2 < NT) stage(t + 2, 0, 0);
        SBAR(); SCHED();
        __builtin_amdgcn_s_setprio(1);
#pragma unroll
        for (int m = 0; m < 8; ++m) {
            acc[m][0] = MFMA16(af[m], bfr[0], acc[m][0]);
            acc[m][1] = MFMA16(af[m], bfr[1], acc[m][1]);
        }
        __builtin_amdgcn_s_setprio(0);
        SBAR(); SCHED();

        // ---- P4: (kk1, n2-3) ----
#pragma unroll
        for (int n = 0; n < 2; ++n)
            bfr[n] = *(const bf16x8*)&Bb[8192 + (wc * 64 + (2 + n) * 16 + lrow) * 32 + kgrp * 8];
        if (t + 2 < NT) {
            stage(t + 2, 1, 0);
            asm volatile("s_waitcnt vmcnt(4)" ::: "memory");
        } else if (t + 1 < NT) {
            asm volatile("s_waitcnt vmcnt(0)" ::: "memory");
        }
        SCHED();
        SBAR(); SCHED();
        __builtin_amdgcn_s_setprio(1);
#pragma unroll
        for (int m = 0; m < 8; ++m) {
            acc[m][2] = MFMA16(af[m], bfr[0], acc[m][2]);
            acc[m][3] = MFMA16(af[m], bfr[1], acc[m][3]);
        }
        __builtin_amdgcn_s_setprio(0);
        SBAR(); SCHED();
    }
}

// ---------------------------------------------------------------------------
// Kernel 1: Mtr[f][d] = (sum_e Wkt[f][e] * Wqt[d][e]) / 32  (scale folded).
// ---------------------------------------------------------------------------
__global__ __launch_bounds__(256) void m_gemm(
    const ushort* __restrict__ Wkt, const ushort* __restrict__ Wqt,
    ushort* __restrict__ Mtr)
{
    __shared__ ushort As[128 * 64];
    __shared__ ushort Bs[128 * 64];
    const int fbase = blockIdx.x * 128;
    const int dbase = blockIdx.y * 128;

    f32x4 acc[4][4];
    mma_tile(Wkt, 1024, fbase, Wqt, 1024, dbase, 16, As, Bs, acc);

    const int lane = threadIdx.x & 63, wid = threadIdx.x >> 6;
    const int wr = wid >> 1, wc = wid & 1;
    const int lrow = lane & 15, kgrp = lane >> 4;
#pragma unroll
    for (int m = 0; m < 4; ++m)
#pragma unroll
        for (int n = 0; n < 4; ++n)
#pragma unroll
            for (int r = 0; r < 4; ++r) {
                const int gf = fbase + wr * 64 + m * 16 + kgrp * 4 + r;
                const int gd = dbase + wc * 64 + n * 16 + lrow;
                Mtr[(size_t)gf * 1024 + gd] = f2bf(acc[m][n][r] * 0.03125f);
            }
}

// ---------------------------------------------------------------------------
// Kernel 2: 8-phase. z=0: T = xb @ Mtr^T -> Tb row-major. z=1: V -> Vt transposed.
// ---------------------------------------------------------------------------
__global__ __launch_bounds__(512, 2) void tv_gemm8(
    const ushort* __restrict__ xb, const ushort* __restrict__ Mtr,
    const ushort* __restrict__ Wvb,
    ushort* __restrict__ Tb, ushort* __restrict__ Vt)
{
    __shared__ ushort As[2 * 2 * 8192];
    __shared__ ushort Bs[2 * 2 * 8192];

    const int z = blockIdx.z;
    const ushort* Bmat = z ? Wvb : Mtr;
    const int mbase = blockIdx.x * 256;
    const int nbase = blockIdx.y * 256;

    f32x4 acc[8][4];
    mma256(xb, 1024, mbase, Bmat, 1024, nbase, 16, As, Bs, acc);

    const int lane = threadIdx.x & 63, w = threadIdx.x >> 6;
    const int wr = w >> 2, wc = w & 3;
    const int lrow = lane & 15, kgrp = lane >> 4;

    if (z == 1) {
        const int b  = mbase >> 11;
        const int s0 = mbase & 2047;
        ushort* VtB = Vt + (size_t)b * 1024 * 2048;
#pragma unroll
        for (int m = 0; m < 8; ++m)
#pragma unroll
            for (int n = 0; n < 4; ++n) {
                u16x4 pk;
#pragma unroll
                for (int r = 0; r < 4; ++r) pk[r] = f2bf(acc[m][n][r]);
                const int d = nbase + wc * 64 + n * 16 + lrow;
                const int s = s0 + wr * 128 + m * 16 + kgrp * 4;
                *(u16x4*)&VtB[(size_t)d * 2048 + s] = pk;
            }
    } else {
#pragma unroll
        for (int m = 0; m < 8; ++m)
#pragma unroll
            for (int n = 0; n < 4; ++n)
#pragma unroll
                for (int r = 0; r < 4; ++r) {
                    const int gr = mbase + wr * 128 + m * 16 + kgrp * 4 + r;
                    const int gc = nbase + wc * 64 + n * 16 + lrow;
                    Tb[(size_t)gr * 1024 + gc] = f2bf(acc[m][n][r]);
                }
    }
}

// ---------------------------------------------------------------------------
// Kernel 3: 8-phase scores, lower-tri 256-tiles. Epilogue applies the causal
// mask and stores UNNORMALIZED p = exp(s) (scores ~N(0,1) -> exp <= ~100,
// safe in bf16). Softmax normalization is folded into pv (row sums there).
// ---------------------------------------------------------------------------
__global__ __launch_bounds__(512, 2) void scores_gemm8(
    const ushort* __restrict__ Tb, const ushort* __restrict__ xb,
    ushort* __restrict__ Sall)
{
    __shared__ ushort As[2 * 2 * 8192];
    __shared__ ushort Bs[2 * 2 * 8192];

    ushort* S = Sall + (size_t)blockIdx.y * 2048 * 2048;
    const int rb = blockIdx.y * 2048;

    int t = blockIdx.x;
    int it = (int)((sqrtf(8.0f * (float)t + 1.0f) - 1.0f) * 0.5f);
    while ((it + 1) * (it + 2) / 2 <= t) ++it;
    while (it * (it + 1) / 2 > t) --it;
    const int jt = t - it * (it + 1) / 2;
    const int ibase = it * 256, jbase = jt * 256;
    const bool diag = (it == jt);

    f32x4 acc[8][4];
    mma256(Tb, 1024, rb + ibase, xb, 1024, rb + jbase, 16, As, Bs, acc);

    const int lane = threadIdx.x & 63, w = threadIdx.x >> 6;
    const int wr = w >> 2, wc = w & 3;
    const int lrow = lane & 15, kgrp = lane >> 4;
#pragma unroll
    for (int m = 0; m < 8; ++m)
#pragma unroll
        for (int n = 0; n < 4; ++n)
#pragma unroll
            for (int r = 0; r < 4; ++r) {
                const int gi = ibase + wr * 128 + m * 16 + kgrp * 4 + r;
                const int gj = jbase + wc * 64 + n * 16 + lrow;
                float p = __expf(acc[m][n][r]);
                if (diag && gj > gi) p = 0.f;
                S[(size_t)gi * 2048 + gj] = f2bf(p);
            }
}

// ---------------------------------------------------------------------------
// PV sub-GEMM: O-rows [it*128, it*128+128) x cols [nbase, nbase+128).
// Fat single-phase, BM=128/BN=128, 8 waves (2 Mrows x 4 Ncols of 32).
// LDS [128][64] full 128-B rows, XOR-16B swizzle: physical granule p holds
// logical granule p^(row&7); staging pre-swizzles the GLOBAL source col
// (linear global_load_lds dest, rule #21 both-sides). Frag reads <=2-way.
// Row-sums of P accumulated in-loop from af (wave handles m==wc slice),
// reduced over kgrp via shfl, shared via rs[] -> epilogue normalizes.
// ---------------------------------------------------------------------------
__device__ __forceinline__ void pv_sub(
    const ushort* __restrict__ P, const ushort* __restrict__ Vt,
    float* __restrict__ O, int it, int nbase,
    ushort* As, ushort* Bs, float* rs)
{
    const int tid  = threadIdx.x;
    const int lane = tid & 63, w = tid >> 6;
    const int wr = w >> 2, wc = w & 3;
    const int lrow = lane & 15, kgrp = lane >> 4;
    const int srow = lane >> 3;             // 0..7 row within 8-row group
    const int sc16 = (lane & 7) ^ srow;     // pre-swizzled source 16B-granule
    const int pbase = it * 128;
    const int NT = 2 * (it + 1);

    auto stage = [&](int t) {
        ushort* dA = As + (size_t)(t & 1) * 8192;
        ushort* dB = Bs + (size_t)(t & 1) * 8192;
#pragma unroll
        for (int i = 0; i < 2; ++i) {
            const int rr = (i * 8 + w) * 8 + srow;   // 0..127
            async16(&P [(size_t)(pbase + rr) * 2048 + t * 64 + sc16 * 8],
                    dA + ((i * 8 + w) * 64 + lane) * 8);
            async16(&Vt[(size_t)(nbase + rr) * 2048 + t * 64 + sc16 * 8],
                    dB + ((i * 8 + w) * 64 + lane) * 8);
        }
    };

    f32x4 acc[4][2];
#pragma unroll
    for (int m = 0; m < 4; ++m)
#pragma unroll
        for (int n = 0; n < 2; ++n) acc[m][n] = (f32x4){0.f, 0.f, 0.f, 0.f};
    float fs = 0.f;

    stage(0);
    if (NT > 1) { stage(1); asm volatile("s_waitcnt vmcnt(4)" ::: "memory"); }
    else        {           asm volatile("s_waitcnt vmcnt(0)" ::: "memory"); }
    SCHED();
    SBAR(); SCHED();

    for (int t = 0; t < NT; ++t) {
        const ushort* Ab = As + (size_t)(t & 1) * 8192;
        const ushort* Bb = Bs + (size_t)(t & 1) * 8192;
        bf16x8 af[2][4], bq[2][2];
#pragma unroll
        for (int kk = 0; kk < 2; ++kk) {
            const int p16 = (kk * 4 + kgrp) ^ (lrow & 7);
#pragma unroll
            for (int m = 0; m < 4; ++m) {
                const int row = wr * 64 + m * 16 + lrow;
                af[kk][m] = *(const bf16x8*)&Ab[row * 64 + p16 * 8];
            }
#pragma unroll
            for (int n = 0; n < 2; ++n) {
                const int row = wc * 32 + n * 16 + lrow;
                bq[kk][n] = *(const bf16x8*)&Bb[row * 64 + p16 * 8];
            }
        }
        asm volatile("s_waitcnt lgkmcnt(0)" ::: "memory");
        SCHED();
        // partial row sums: this wave covers the m == wc slice of rows
#pragma unroll
        for (int kk = 0; kk < 2; ++kk)
#pragma unroll
            for (int m = 0; m < 4; ++m)
                if (m == wc) {
#pragma unroll
                    for (int e = 0; e < 8; ++e)
                        fs += bf2f((ushort)af[kk][m][e]);
                }
        SBAR(); SCHED();                   // buf[t&1] fully read -> released
        if (t + 2 < NT) {
            stage(t + 2);
            asm volatile("s_waitcnt vmcnt(4)" ::: "memory");  // t+1 complete
        } else if (t + 1 < NT) {
            asm volatile("s_waitcnt vmcnt(0)" ::: "memory");
        }
        SCHED();
        SBAR(); SCHED();                   // t+1 resident for all waves
        __builtin_amdgcn_s_setprio(1);
#pragma unroll
        for (int kk = 0; kk < 2; ++kk)
#pragma unroll
            for (int m = 0; m < 4; ++m) {
                acc[m][0] = MFMA16(af[kk][m], bq[kk][0], acc[m][0]);
                acc[m][1] = MFMA16(af[kk][m], bq[kk][1], acc[m][1]);
            }
        __builtin_amdgcn_s_setprio(0);
    }

    // reduce partial sums over kgrp (lanes l, l^16, l^32, l^48 share lrow)
    fs += __shfl_xor(fs, 16);
    fs += __shfl_xor(fs, 32);
    if (lane < 16) rs[wr * 64 + wc * 16 + lane] = fs;
    __syncthreads();

#pragma unroll
    for (int m = 0; m < 4; ++m)
#pragma unroll
        for (int r = 0; r < 4; ++r) {
            const int ri = wr * 64 + m * 16 + kgrp * 4 + r;
            const float inv = 1.0f / rs[ri];
            const int gi = pbase + ri;
#pragma unroll
            for (int n = 0; n < 2; ++n) {
                const int gc = nbase + wc * 32 + n * 16 + lrow;
                O[(size_t)gi * 1024 + gc] = acc[m][n][r] * inv;
            }
        }
    __syncthreads();
}

// ---------------------------------------------------------------------------
// Kernel 4: O = P @ V with fused softmax-normalize. Paired row-tiles
// (it, 15-it): every block does exactly 34 k-tiles -> perfectly balanced.
// grid (8 pairs, 8 nc, 4 b) = 256 blocks = 1/CU.
// ---------------------------------------------------------------------------
__global__ __launch_bounds__(512, 2) void pv_pair(
    const ushort* __restrict__ Pall, const ushort* __restrict__ Vtall,
    float* __restrict__ Oall)
{
    __shared__ ushort As[2 * 8192];   // 32 KiB
    __shared__ ushort Bs[2 * 8192];   // 32 KiB
    __shared__ float rs[128];

    const ushort* P  = Pall  + (size_t)blockIdx.z * 2048 * 2048;
    const ushort* Vt = Vtall + (size_t)blockIdx.z * 1024 * 2048;
    float*        O  = Oall  + (size_t)blockIdx.z * 2048 * 1024;
    const int nbase = blockIdx.y * 128;

    pv_sub(P, Vt, O, 15 - (int)blockIdx.x, nbase, As, Bs, rs);
    pv_sub(P, Vt, O, (int)blockIdx.x,      nbase, As, Bs, rs);
}

// ---------------------------------------------------------------------------
extern "C" void kernel_launch(void* const* d_in, const int* in_sizes, int n_in,
                              void* d_out, int out_size, void* d_ws, size_t ws_size,
                              hipStream_t stream)
{
    (void)in_sizes; (void)n_in; (void)out_size; (void)ws_size;
    const float* x  = (const float*)d_in[0];
    const float* Wk = (const float*)d_in[1];
    const float* Wq = (const float*)d_in[2];
    const float* Wv = (const float*)d_in[3];
    float* out = (float*)d_out;

    const size_t M1 = (size_t)1024 * 1024;
    ushort* ws  = (ushort*)d_ws;
    ushort* xb  = ws;                      // 8M elems
    ushort* Tb  = xb  + 8 * M1;            // 8M
    ushort* Vt  = Tb  + 8 * M1;            // 8M (4 x [1024][2048])
    ushort* Sb  = Vt  + 8 * M1;            // 16M (4 x [2048][2048])
    ushort* Wkt = Sb  + 16 * M1;           // 1M
    ushort* Wqt = Wkt + M1;                // 1M
    ushort* Wvb = Wqt + M1;                // 1M
    ushort* Mtr = Wvb + M1;                // 1M

    // 0) fused conversions (x, Wv straight; Wk, Wq transposed)
    cvt_all<<<6656, 256, 0, stream>>>(x, Wk, Wq, Wv, xb, Wvb, Wkt, Wqt);
    // 1) M = (Wq^T Wk)/32 stored transposed
    m_gemm<<<dim3(8, 8), 256, 0, stream>>>(Wkt, Wqt, Mtr);
    // 2) T = x@M (z=0), V^T (z=1); 256 blocks = 1/CU
    tv_gemm8<<<dim3(32, 4, 2), 512, 0, stream>>>(xb, Mtr, Wvb, Tb, Vt);
    // 3) scores -> exp(s) with causal mask (unnormalized), lower-tri 256-tiles
    scores_gemm8<<<dim3(36, 4), 512, 0, stream>>>(Tb, xb, Sb);
    // 4) O = P @ V with fused normalize, balanced paired row-tiles
    pv_pair<<<dim3(8, 8, 4), 512, 0, stream>>>(Sb, Vt, out);
}

// Round 8
// 150.484 us; speedup vs baseline: 1.2028x; 1.0417x over previous
//
#include <hip/hip_runtime.h>

typedef __attribute__((ext_vector_type(8))) short bf16x8;
typedef __attribute__((ext_vector_type(4))) float f32x4;
typedef __attribute__((ext_vector_type(4))) unsigned short u16x4;
typedef __attribute__((ext_vector_type(8))) unsigned short u16x8;

#define MFMA16(a, b, c) __builtin_amdgcn_mfma_f32_16x16x32_bf16((a), (b), (c), 0, 0, 0)

__device__ __forceinline__ ushort f2bf(float f) {
    unsigned u = __float_as_uint(f);
    unsigned r = (u + 0x7FFFu + ((u >> 16) & 1u)) >> 16;
    return (ushort)r;
}
__device__ __forceinline__ float bf2f(ushort s) {
    return __uint_as_float(((unsigned)s) << 16);
}

// async global->LDS, 16B per lane. LDS dest is wave-uniform base + lane*16.
__device__ __forceinline__ void async16(const ushort* g, ushort* l) {
    __builtin_amdgcn_global_load_lds(
        (const __attribute__((address_space(1))) unsigned*)g,
        (__attribute__((address_space(3))) unsigned*)l, 16, 0, 0);
}

#define SBAR()  __builtin_amdgcn_s_barrier()
#define SCHED() __builtin_amdgcn_sched_barrier(0)

// ---------------------------------------------------------------------------
// Kernel 0: fused conversions.
// blocks [0,4608): straight fp32->bf16 of x and Wv.
// blocks [4608,6656): 32x32 transpose-convert of Wk (z=0) and Wq (z=1).
// ---------------------------------------------------------------------------
__global__ __launch_bounds__(256) void cvt_all(
    const float* __restrict__ x,  const float* __restrict__ wk,
    const float* __restrict__ wq, const float* __restrict__ wv,
    ushort* __restrict__ xb,  ushort* __restrict__ wvb,
    ushort* __restrict__ wkt, ushort* __restrict__ wqt)
{
    __shared__ float t[32][33];
    int bx = blockIdx.x;
    if (bx < 4608) {
        const size_t XN = (size_t)8192 * 1024;
        size_t idx = ((size_t)bx * 256 + threadIdx.x) * 8;
        const float* s;
        ushort* d;
        if (idx < XN) { s = x + idx; d = xb + idx; }
        else          { s = wv + (idx - XN); d = wvb + (idx - XN); }
        float4 a = *(const float4*)s;
        float4 b = *(const float4*)(s + 4);
        u16x8 p;
        p[0] = f2bf(a.x); p[1] = f2bf(a.y); p[2] = f2bf(a.z); p[3] = f2bf(a.w);
        p[4] = f2bf(b.x); p[5] = f2bf(b.y); p[6] = f2bf(b.z); p[7] = f2bf(b.w);
        *(u16x8*)d = p;
    } else {
        bx -= 4608;
        const int z  = bx >> 10;
        const int tb = bx & 1023;
        const int e0 = (tb & 31) * 32, d0 = (tb >> 5) * 32;
        const float* src = z ? wq : wk;
        ushort*      dst = z ? wqt : wkt;
        const int tx = threadIdx.x & 31, ty = threadIdx.x >> 5;
#pragma unroll
        for (int r = 0; r < 4; ++r)
            t[ty + 8 * r][tx] = src[(size_t)(e0 + ty + 8 * r) * 1024 + d0 + tx];
        __syncthreads();
#pragma unroll
        for (int r = 0; r < 4; ++r)
            dst[(size_t)(d0 + ty + 8 * r) * 1024 + e0 + tx] = f2bf(t[tx][ty + 8 * r]);
    }
}

// ---------------------------------------------------------------------------
// 2-phase 128x128 core (kept for m_gemm). 256 threads.
// ---------------------------------------------------------------------------
__device__ __forceinline__ void mma_tile(
    const ushort* __restrict__ A, int lda, int abase,
    const ushort* __restrict__ B, int ldb, int bbase,
    int ktiles,
    ushort* As, ushort* Bs, f32x4 (&acc)[4][4])
{
    const int tid  = threadIdx.x;
    const int lane = tid & 63, wid = tid >> 6;
    const int wr = wid >> 1, wc = wid & 1;
    const int lrow = lane & 15, kgrp = lane >> 4;
    const int ci = lane >> 3;
    const int cc = (lane & 7) * 8;

#pragma unroll
    for (int m = 0; m < 4; ++m)
#pragma unroll
        for (int n = 0; n < 4; ++n) acc[m][n] = (f32x4){0.f, 0.f, 0.f, 0.f};

    for (int kt = 0; kt < ktiles; ++kt) {
        const int k0 = kt * 64;
#pragma unroll
        for (int i = 0; i < 4; ++i) {
            const int r = (wid * 4 + i) * 8 + ci;
            async16(&A[(size_t)(abase + r) * lda + k0 + cc], &As[(wid * 4 + i) * 512]);
            async16(&B[(size_t)(bbase + r) * ldb + k0 + cc], &Bs[(wid * 4 + i) * 512]);
        }
        __syncthreads();
#pragma unroll
        for (int kk = 0; kk < 2; ++kk) {
            bf16x8 af[4], bfr[4];
#pragma unroll
            for (int m = 0; m < 4; ++m)
                af[m] = *(const bf16x8*)&As[(wr * 64 + m * 16 + lrow) * 64 + kk * 32 + kgrp * 8];
#pragma unroll
            for (int n = 0; n < 4; ++n)
                bfr[n] = *(const bf16x8*)&Bs[(wc * 64 + n * 16 + lrow) * 64 + kk * 32 + kgrp * 8];
#pragma unroll
            for (int m = 0; m < 4; ++m)
#pragma unroll
                for (int n = 0; n < 4; ++n)
                    acc[m][n] = MFMA16(af[m], bfr[n], acc[m][n]);
        }
        __syncthreads();
    }
}

// ---------------------------------------------------------------------------
// 8-phase 256x256 core (tv, scores). 512 threads = 8 waves (2x4).
// LDS per operand: [2 buf][256 rows][64 elems] (128-B rows), 16-B-granule
// XOR swizzle phys = logical ^ (row&7). Staged via pre-swizzled GLOBAL
// source granule (linear global_load_lds dest, rule #21 both-sides).
// Frag reads: quarter-wave spreads over 8 granule-positions -> 2-way (free).
// Stage map (race-free with shared-row kk): P1: B(t+1) lo, P2: B(t+1) hi,
// P4: A(t+2) lo+hi, vmcnt(4) -> t+1 fully resident at t.P4's barrier.
// ---------------------------------------------------------------------------
__device__ __forceinline__ void mma256(
    const ushort* __restrict__ A, int lda, int abase,
    const ushort* __restrict__ B, int ldb, int bbase,
    int NT, ushort* As, ushort* Bs, f32x4 (&acc)[8][4])
{
    const int tid  = threadIdx.x;
    const int lane = tid & 63, w = tid >> 6;
    const int wr = w >> 2, wc = w & 3;
    const int lrow = lane & 15, kgrp = lane >> 4;
    const int sgl  = ((lane & 7) ^ ((lane >> 3) & 7)) * 8;  // pre-swizzled src granule
    const int srow = lane >> 3;                             // row within 8-row chunk

    // stage 128 rows (hi half or lo half) of one operand for K-tile t.
    auto stage = [&](int t, int isB, int hi) {
        const ushort* src = isB ? B : A;
        const int ld = isB ? ldb : lda;
        const int rb = isB ? bbase : abase;
        ushort* buf = (isB ? Bs : As) + (size_t)(t & 1) * 16384;
#pragma unroll
        for (int i = 0; i < 2; ++i) {
            const int r = hi * 128 + (w * 2 + i) * 8 + srow;
            async16(&src[(size_t)(rb + r) * ld + t * 64 + sgl],
                    buf + (size_t)(hi * 128 + (w * 2 + i) * 8) * 64 + lane * 8);
        }
    };

#pragma unroll
    for (int m = 0; m < 8; ++m)
#pragma unroll
        for (int n = 0; n < 4; ++n) acc[m][n] = (f32x4){0.f, 0.f, 0.f, 0.f};

    // prologue: tile 0 complete (A lo/hi, B lo/hi), then tile 1's A chunks
    stage(0, 0, 0); stage(0, 0, 1); stage(0, 1, 0); stage(0, 1, 1);
    if (NT > 1) {
        stage(1, 0, 0); stage(1, 0, 1);
        asm volatile("s_waitcnt vmcnt(4)" ::: "memory");   // tile 0 resident
    } else {
        asm volatile("s_waitcnt vmcnt(0)" ::: "memory");
    }
    SCHED();
    SBAR();
    SCHED();

    const int sw = lrow & 7;   // row-derived XOR for frag reads

    for (int t = 0; t < NT; ++t) {
        ushort* Ab = As + (size_t)(t & 1) * 16384;
        ushort* Bb = Bs + (size_t)(t & 1) * 16384;
        bf16x8 af[8], bfr[2];

        // ---- P1: (kk0, n0-1) ----
        {
            const int g = (kgrp ^ sw) * 8;
#pragma unroll
            for (int m = 0; m < 8; ++m)
                af[m] = *(const bf16x8*)&Ab[(wr * 128 + m * 16 + lrow) * 64 + g];
#pragma unroll
            for (int n = 0; n < 2; ++n)
                bfr[n] = *(const bf16x8*)&Bb[(wc * 64 + n * 16 + lrow) * 64 + g];
        }
        if (t + 1 < NT) stage(t + 1, 1, 0);
        SBAR(); SCHED();
        __builtin_amdgcn_s_setprio(1);
#pragma unroll
        for (int m = 0; m < 8; ++m) {
            acc[m][0] = MFMA16(af[m], bfr[0], acc[m][0]);
            acc[m][1] = MFMA16(af[m], bfr[1], acc[m][1]);
        }
        __builtin_amdgcn_s_setprio(0);
        SBAR(); SCHED();

        // ---- P2: (kk0, n2-3) ----
        {
            const int g = (kgrp ^ sw) * 8;
#pragma unroll
            for (int n = 0; n < 2; ++n)
                bfr[n] = *(const bf16x8*)&Bb[(wc * 64 + (2 + n) * 16 + lrow) * 64 + g];
        }
        if (t + 1 < NT) stage(t + 1, 1, 1);
        SBAR(); SCHED();
        __builtin_amdgcn_s_setprio(1);
#pragma unroll
        for (int m = 0; m < 8; ++m) {
            acc[m][2] = MFMA16(af[m], bfr[0], acc[m][2]);
            acc[m][3] = MFMA16(af[m], bfr[1], acc[m][3]);
        }
        __builtin_amdgcn_s_setprio(0);
        SBAR(); SCHED();

        // ---- P3: (kk1, n0-1) ----
        {
            const int g = ((4 + kgrp) ^ sw) * 8;
#pragma unroll
            for (int m = 0; m < 8; ++m)
                af[m] = *(const bf16x8*)&Ab[(wr * 128 + m * 16 + lrow) * 64 + g];
#pragma unroll
            for (int n = 0; n < 2; ++n)
                bfr[n] = *(const bf16x8*)&Bb[(wc * 64 + n * 16 + lrow) * 64 + g];
        }
        SBAR(); SCHED();
        __builtin_amdgcn_s_setprio(1);
#pragma unroll
        for (int m = 0; m < 8; ++m) {
            acc[m][0] = MFMA16(af[m], bfr[0], acc[m][0]);
            acc[m][1] = MFMA16(af[m], bfr[1], acc[m][1]);
        }
        __builtin_amdgcn_s_setprio(0);
        SBAR(); SCHED();

        // ---- P4: (kk1, n2-3) ----
        {
            const int g = ((4 + kgrp) ^ sw) * 8;
#pragma unroll
            for (int n = 0; n < 2; ++n)
                bfr[n] = *(const bf16x8*)&Bb[(wc * 64 + (2 + n) * 16 + lrow) * 64 + g];
        }
        if (t + 2 < NT) {
            stage(t + 2, 0, 0); stage(t + 2, 0, 1);
            asm volatile("s_waitcnt vmcnt(4)" ::: "memory");   // t+1 resident
        } else if (t + 1 < NT) {
            asm volatile("s_waitcnt vmcnt(0)" ::: "memory");
        }
        SCHED();
        SBAR(); SCHED();
        __builtin_amdgcn_s_setprio(1);
#pragma unroll
        for (int m = 0; m < 8; ++m) {
            acc[m][2] = MFMA16(af[m], bfr[0], acc[m][2]);
            acc[m][3] = MFMA16(af[m], bfr[1], acc[m][3]);
        }
        __builtin_amdgcn_s_setprio(0);
        SBAR(); SCHED();
    }
}

// ---------------------------------------------------------------------------
// Kernel 1: Mtr[f][d] = (sum_e Wkt[f][e] * Wqt[d][e]) / 32  (scale folded).
// ---------------------------------------------------------------------------
__global__ __launch_bounds__(256) void m_gemm(
    const ushort* __restrict__ Wkt, const ushort* __restrict__ Wqt,
    ushort* __restrict__ Mtr)
{
    __shared__ ushort As[128 * 64];
    __shared__ ushort Bs[128 * 64];
    const int fbase = blockIdx.x * 128;
    const int dbase = blockIdx.y * 128;

    f32x4 acc[4][4];
    mma_tile(Wkt, 1024, fbase, Wqt, 1024, dbase, 16, As, Bs, acc);

    const int lane = threadIdx.x & 63, wid = threadIdx.x >> 6;
    const int wr = wid >> 1, wc = wid & 1;
    const int lrow = lane & 15, kgrp = lane >> 4;
#pragma unroll
    for (int m = 0; m < 4; ++m)
#pragma unroll
        for (int n = 0; n < 4; ++n)
#pragma unroll
            for (int r = 0; r < 4; ++r) {
                const int gf = fbase + wr * 64 + m * 16 + kgrp * 4 + r;
                const int gd = dbase + wc * 64 + n * 16 + lrow;
                Mtr[(size_t)gf * 1024 + gd] = f2bf(acc[m][n][r] * 0.03125f);
            }
}

// ---------------------------------------------------------------------------
// Kernel 2: 8-phase. z=0: T = xb @ Mtr^T -> Tb row-major. z=1: V -> Vt transposed.
// ---------------------------------------------------------------------------
__global__ __launch_bounds__(512, 2) void tv_gemm8(
    const ushort* __restrict__ xb, const ushort* __restrict__ Mtr,
    const ushort* __restrict__ Wvb,
    ushort* __restrict__ Tb, ushort* __restrict__ Vt)
{
    __shared__ ushort As[2 * 16384];
    __shared__ ushort Bs[2 * 16384];

    const int z = blockIdx.z;
    const ushort* Bmat = z ? Wvb : Mtr;
    const int mbase = blockIdx.x * 256;
    const int nbase = blockIdx.y * 256;

    f32x4 acc[8][4];
    mma256(xb, 1024, mbase, Bmat, 1024, nbase, 16, As, Bs, acc);

    const int lane = threadIdx.x & 63, w = threadIdx.x >> 6;
    const int wr = w >> 2, wc = w & 3;
    const int lrow = lane & 15, kgrp = lane >> 4;

    if (z == 1) {
        const int b  = mbase >> 11;
        const int s0 = mbase & 2047;
        ushort* VtB = Vt + (size_t)b * 1024 * 2048;
#pragma unroll
        for (int m = 0; m < 8; ++m)
#pragma unroll
            for (int n = 0; n < 4; ++n) {
                u16x4 pk;
#pragma unroll
                for (int r = 0; r < 4; ++r) pk[r] = f2bf(acc[m][n][r]);
                const int d = nbase + wc * 64 + n * 16 + lrow;
                const int s = s0 + wr * 128 + m * 16 + kgrp * 4;
                *(u16x4*)&VtB[(size_t)d * 2048 + s] = pk;
            }
    } else {
#pragma unroll
        for (int m = 0; m < 8; ++m)
#pragma unroll
            for (int n = 0; n < 4; ++n)
#pragma unroll
                for (int r = 0; r < 4; ++r) {
                    const int gr = mbase + wr * 128 + m * 16 + kgrp * 4 + r;
                    const int gc = nbase + wc * 64 + n * 16 + lrow;
                    Tb[(size_t)gr * 1024 + gc] = f2bf(acc[m][n][r]);
                }
    }
}

// ---------------------------------------------------------------------------
// Kernel 3: 8-phase scores, lower-tri 256-tiles. Epilogue applies the causal
// mask and stores UNNORMALIZED p = exp(s) (scores ~N(0,1) -> exp <= ~100,
// safe in bf16). Softmax normalization is folded into pv (row sums there).
// ---------------------------------------------------------------------------
__global__ __launch_bounds__(512, 2) void scores_gemm8(
    const ushort* __restrict__ Tb, const ushort* __restrict__ xb,
    ushort* __restrict__ Sall)
{
    __shared__ ushort As[2 * 16384];
    __shared__ ushort Bs[2 * 16384];

    ushort* S = Sall + (size_t)blockIdx.y * 2048 * 2048;
    const int rb = blockIdx.y * 2048;

    int t = blockIdx.x;
    int it = (int)((sqrtf(8.0f * (float)t + 1.0f) - 1.0f) * 0.5f);
    while ((it + 1) * (it + 2) / 2 <= t) ++it;
    while (it * (it + 1) / 2 > t) --it;
    const int jt = t - it * (it + 1) / 2;
    const int ibase = it * 256, jbase = jt * 256;
    const bool diag = (it == jt);

    f32x4 acc[8][4];
    mma256(Tb, 1024, rb + ibase, xb, 1024, rb + jbase, 16, As, Bs, acc);

    const int lane = threadIdx.x & 63, w = threadIdx.x >> 6;
    const int wr = w >> 2, wc = w & 3;
    const int lrow = lane & 15, kgrp = lane >> 4;
#pragma unroll
    for (int m = 0; m < 8; ++m)
#pragma unroll
        for (int n = 0; n < 4; ++n)
#pragma unroll
            for (int r = 0; r < 4; ++r) {
                const int gi = ibase + wr * 128 + m * 16 + kgrp * 4 + r;
                const int gj = jbase + wc * 64 + n * 16 + lrow;
                float p = __expf(acc[m][n][r]);
                if (diag && gj > gi) p = 0.f;
                S[(size_t)gi * 2048 + gj] = f2bf(p);
            }
}

// ---------------------------------------------------------------------------
// PV sub-GEMM: O-rows [it*128, it*128+128) x cols [nbase, nbase+128).
// Fat single-phase, BM=128/BN=128, 8 waves (2 Mrows x 4 Ncols of 32).
// LDS [128][64] full 128-B rows, XOR-16B swizzle (rule #21 both-sides).
// Row-sums of P accumulated in-loop from af; epilogue normalizes.
// ---------------------------------------------------------------------------
__device__ __forceinline__ void pv_sub(
    const ushort* __restrict__ P, const ushort* __restrict__ Vt,
    float* __restrict__ O, int it, int nbase,
    ushort* As, ushort* Bs, float* rs)
{
    const int tid  = threadIdx.x;
    const int lane = tid & 63, w = tid >> 6;
    const int wr = w >> 2, wc = w & 3;
    const int lrow = lane & 15, kgrp = lane >> 4;
    const int srow = lane >> 3;             // 0..7 row within 8-row group
    const int sc16 = (lane & 7) ^ srow;     // pre-swizzled source 16B-granule
    const int pbase = it * 128;
    const int NT = 2 * (it + 1);

    auto stage = [&](int t) {
        ushort* dA = As + (size_t)(t & 1) * 8192;
        ushort* dB = Bs + (size_t)(t & 1) * 8192;
#pragma unroll
        for (int i = 0; i < 2; ++i) {
            const int rr = (i * 8 + w) * 8 + srow;   // 0..127
            async16(&P [(size_t)(pbase + rr) * 2048 + t * 64 + sc16 * 8],
                    dA + ((i * 8 + w) * 64 + lane) * 8);
            async16(&Vt[(size_t)(nbase + rr) * 2048 + t * 64 + sc16 * 8],
                    dB + ((i * 8 + w) * 64 + lane) * 8);
        }
    };

    f32x4 acc[4][2];
#pragma unroll
    for (int m = 0; m < 4; ++m)
#pragma unroll
        for (int n = 0; n < 2; ++n) acc[m][n] = (f32x4){0.f, 0.f, 0.f, 0.f};
    float fs = 0.f;

    stage(0);
    if (NT > 1) { stage(1); asm volatile("s_waitcnt vmcnt(4)" ::: "memory"); }
    else        {           asm volatile("s_waitcnt vmcnt(0)" ::: "memory"); }
    SCHED();
    SBAR(); SCHED();

    for (int t = 0; t < NT; ++t) {
        const ushort* Ab = As + (size_t)(t & 1) * 8192;
        const ushort* Bb = Bs + (size_t)(t & 1) * 8192;
        bf16x8 af[2][4], bq[2][2];
#pragma unroll
        for (int kk = 0; kk < 2; ++kk) {
            const int p16 = (kk * 4 + kgrp) ^ (lrow & 7);
#pragma unroll
            for (int m = 0; m < 4; ++m) {
                const int row = wr * 64 + m * 16 + lrow;
                af[kk][m] = *(const bf16x8*)&Ab[row * 64 + p16 * 8];
            }
#pragma unroll
            for (int n = 0; n < 2; ++n) {
                const int row = wc * 32 + n * 16 + lrow;
                bq[kk][n] = *(const bf16x8*)&Bb[row * 64 + p16 * 8];
            }
        }
        asm volatile("s_waitcnt lgkmcnt(0)" ::: "memory");
        SCHED();
        // partial row sums: this wave covers the m == wc slice of rows
#pragma unroll
        for (int kk = 0; kk < 2; ++kk)
#pragma unroll
            for (int m = 0; m < 4; ++m)
                if (m == wc) {
#pragma unroll
                    for (int e = 0; e < 8; ++e)
                        fs += bf2f((ushort)af[kk][m][e]);
                }
        SBAR(); SCHED();                   // buf[t&1] fully read -> released
        if (t + 2 < NT) {
            stage(t + 2);
            asm volatile("s_waitcnt vmcnt(4)" ::: "memory");  // t+1 complete
        } else if (t + 1 < NT) {
            asm volatile("s_waitcnt vmcnt(0)" ::: "memory");
        }
        SCHED();
        SBAR(); SCHED();                   // t+1 resident for all waves
        __builtin_amdgcn_s_setprio(1);
#pragma unroll
        for (int kk = 0; kk < 2; ++kk)
#pragma unroll
            for (int m = 0; m < 4; ++m) {
                acc[m][0] = MFMA16(af[kk][m], bq[kk][0], acc[m][0]);
                acc[m][1] = MFMA16(af[kk][m], bq[kk][1], acc[m][1]);
            }
        __builtin_amdgcn_s_setprio(0);
    }

    // reduce partial sums over kgrp (lanes l, l^16, l^32, l^48 share lrow)
    fs += __shfl_xor(fs, 16);
    fs += __shfl_xor(fs, 32);
    if (lane < 16) rs[wr * 64 + wc * 16 + lane] = fs;
    __syncthreads();

#pragma unroll
    for (int m = 0; m < 4; ++m)
#pragma unroll
        for (int r = 0; r < 4; ++r) {
            const int ri = wr * 64 + m * 16 + kgrp * 4 + r;
            const float inv = 1.0f / rs[ri];
            const int gi = pbase + ri;
#pragma unroll
            for (int n = 0; n < 2; ++n) {
                const int gc = nbase + wc * 32 + n * 16 + lrow;
                O[(size_t)gi * 1024 + gc] = acc[m][n][r] * inv;
            }
        }
    __syncthreads();
}

// ---------------------------------------------------------------------------
// Kernel 4: O = P @ V with fused softmax-normalize. Paired row-tiles
// (it, 15-it): every block does exactly 34 k-tiles -> perfectly balanced.
// grid (8 pairs, 8 nc, 4 b) = 256 blocks = 1/CU.
// ---------------------------------------------------------------------------
__global__ __launch_bounds__(512, 2) void pv_pair(
    const ushort* __restrict__ Pall, const ushort* __restrict__ Vtall,
    float* __restrict__ Oall)
{
    __shared__ ushort As[2 * 8192];   // 32 KiB
    __shared__ ushort Bs[2 * 8192];   // 32 KiB
    __shared__ float rs[128];

    const ushort* P  = Pall  + (size_t)blockIdx.z * 2048 * 2048;
    const ushort* Vt = Vtall + (size_t)blockIdx.z * 1024 * 2048;
    float*        O  = Oall  + (size_t)blockIdx.z * 2048 * 1024;
    const int nbase = blockIdx.y * 128;

    pv_sub(P, Vt, O, 15 - (int)blockIdx.x, nbase, As, Bs, rs);
    pv_sub(P, Vt, O, (int)blockIdx.x,      nbase, As, Bs, rs);
}

// ---------------------------------------------------------------------------
extern "C" void kernel_launch(void* const* d_in, const int* in_sizes, int n_in,
                              void* d_out, int out_size, void* d_ws, size_t ws_size,
                              hipStream_t stream)
{
    (void)in_sizes; (void)n_in; (void)out_size; (void)ws_size;
    const float* x  = (const float*)d_in[0];
    const float* Wk = (const float*)d_in[1];
    const float* Wq = (const float*)d_in[2];
    const float* Wv = (const float*)d_in[3];
    float* out = (float*)d_out;

    const size_t M1 = (size_t)1024 * 1024;
    ushort* ws  = (ushort*)d_ws;
    ushort* xb  = ws;                      // 8M elems
    ushort* Tb  = xb  + 8 * M1;            // 8M
    ushort* Vt  = Tb  + 8 * M1;            // 8M (4 x [1024][2048])
    ushort* Sb  = Vt  + 8 * M1;            // 16M (4 x [2048][2048])
    ushort* Wkt = Sb  + 16 * M1;           // 1M
    ushort* Wqt = Wkt + M1;                // 1M
    ushort* Wvb = Wqt + M1;                // 1M
    ushort* Mtr = Wvb + M1;                // 1M

    // 0) fused conversions (x, Wv straight; Wk, Wq transposed)
    cvt_all<<<6656, 256, 0, stream>>>(x, Wk, Wq, Wv, xb, Wvb, Wkt, Wqt);
    // 1) M = (Wq^T Wk)/32 stored transposed
    m_gemm<<<dim3(8, 8), 256, 0, stream>>>(Wkt, Wqt, Mtr);
    // 2) T = x@M (z=0), V^T (z=1); 256 blocks = 1/CU
    tv_gemm8<<<dim3(32, 4, 2), 512, 0, stream>>>(xb, Mtr, Wvb, Tb, Vt);
    // 3) scores -> exp(s) with causal mask (unnormalized), lower-tri 256-tiles
    scores_gemm8<<<dim3(36, 4), 512, 0, stream>>>(Tb, xb, Sb);
    // 4) O = P @ V with fused normalize, balanced paired row-tiles
    pv_pair<<<dim3(8, 8, 4), 512, 0, stream>>>(Sb, Vt, out);
}

// Round 10
// 149.159 us; speedup vs baseline: 1.2135x; 1.0089x over previous
//
#include <hip/hip_runtime.h>

typedef __attribute__((ext_vector_type(8))) short bf16x8;
typedef __attribute__((ext_vector_type(4))) float f32x4;
typedef __attribute__((ext_vector_type(4))) unsigned short u16x4;
typedef __attribute__((ext_vector_type(8))) unsigned short u16x8;

#define MFMA16(a, b, c) __builtin_amdgcn_mfma_f32_16x16x32_bf16((a), (b), (c), 0, 0, 0)

__device__ __forceinline__ ushort f2bf(float f) {
    unsigned u = __float_as_uint(f);
    unsigned r = (u + 0x7FFFu + ((u >> 16) & 1u)) >> 16;
    return (ushort)r;
}
__device__ __forceinline__ float bf2f(ushort s) {
    return __uint_as_float(((unsigned)s) << 16);
}

// async global->LDS, 16B per lane. LDS dest is wave-uniform base + lane*16.
__device__ __forceinline__ void async16(const ushort* g, ushort* l) {
    __builtin_amdgcn_global_load_lds(
        (const __attribute__((address_space(1))) unsigned*)g,
        (__attribute__((address_space(3))) unsigned*)l, 16, 0, 0);
}

#define SBAR()  __builtin_amdgcn_s_barrier()
#define SCHED() __builtin_amdgcn_sched_barrier(0)

// ---------------------------------------------------------------------------
// Kernel 0: fused conversions.
// blocks [0,4608): straight fp32->bf16 of x and Wv.
// blocks [4608,6656): 32x32 transpose-convert of Wk (z=0) and Wq (z=1).
// ---------------------------------------------------------------------------
__global__ __launch_bounds__(256) void cvt_all(
    const float* __restrict__ x,  const float* __restrict__ wk,
    const float* __restrict__ wq, const float* __restrict__ wv,
    ushort* __restrict__ xb,  ushort* __restrict__ wvb,
    ushort* __restrict__ wkt, ushort* __restrict__ wqt)
{
    __shared__ float t[32][33];
    int bx = blockIdx.x;
    if (bx < 4608) {
        const size_t XN = (size_t)8192 * 1024;
        size_t idx = ((size_t)bx * 256 + threadIdx.x) * 8;
        const float* s;
        ushort* d;
        if (idx < XN) { s = x + idx; d = xb + idx; }
        else          { s = wv + (idx - XN); d = wvb + (idx - XN); }
        float4 a = *(const float4*)s;
        float4 b = *(const float4*)(s + 4);
        u16x8 p;
        p[0] = f2bf(a.x); p[1] = f2bf(a.y); p[2] = f2bf(a.z); p[3] = f2bf(a.w);
        p[4] = f2bf(b.x); p[5] = f2bf(b.y); p[6] = f2bf(b.z); p[7] = f2bf(b.w);
        *(u16x8*)d = p;
    } else {
        bx -= 4608;
        const int z  = bx >> 10;
        const int tb = bx & 1023;
        const int e0 = (tb & 31) * 32, d0 = (tb >> 5) * 32;
        const float* src = z ? wq : wk;
        ushort*      dst = z ? wqt : wkt;
        const int tx = threadIdx.x & 31, ty = threadIdx.x >> 5;
#pragma unroll
        for (int r = 0; r < 4; ++r)
            t[ty + 8 * r][tx] = src[(size_t)(e0 + ty + 8 * r) * 1024 + d0 + tx];
        __syncthreads();
#pragma unroll
        for (int r = 0; r < 4; ++r)
            dst[(size_t)(d0 + ty + 8 * r) * 1024 + e0 + tx] = f2bf(t[tx][ty + 8 * r]);
    }
}

// ---------------------------------------------------------------------------
// 2-phase 128x128 core (kept for m_gemm). 256 threads.
// ---------------------------------------------------------------------------
__device__ __forceinline__ void mma_tile(
    const ushort* __restrict__ A, int lda, int abase,
    const ushort* __restrict__ B, int ldb, int bbase,
    int ktiles,
    ushort* As, ushort* Bs, f32x4 (&acc)[4][4])
{
    const int tid  = threadIdx.x;
    const int lane = tid & 63, wid = tid >> 6;
    const int wr = wid >> 1, wc = wid & 1;
    const int lrow = lane & 15, kgrp = lane >> 4;
    const int ci = lane >> 3;
    const int cc = (lane & 7) * 8;

#pragma unroll
    for (int m = 0; m < 4; ++m)
#pragma unroll
        for (int n = 0; n < 4; ++n) acc[m][n] = (f32x4){0.f, 0.f, 0.f, 0.f};

    for (int kt = 0; kt < ktiles; ++kt) {
        const int k0 = kt * 64;
#pragma unroll
        for (int i = 0; i < 4; ++i) {
            const int r = (wid * 4 + i) * 8 + ci;
            async16(&A[(size_t)(abase + r) * lda + k0 + cc], &As[(wid * 4 + i) * 512]);
            async16(&B[(size_t)(bbase + r) * ldb + k0 + cc], &Bs[(wid * 4 + i) * 512]);
        }
        __syncthreads();
#pragma unroll
        for (int kk = 0; kk < 2; ++kk) {
            bf16x8 af[4], bfr[4];
#pragma unroll
            for (int m = 0; m < 4; ++m)
                af[m] = *(const bf16x8*)&As[(wr * 64 + m * 16 + lrow) * 64 + kk * 32 + kgrp * 8];
#pragma unroll
            for (int n = 0; n < 4; ++n)
                bfr[n] = *(const bf16x8*)&Bs[(wc * 64 + n * 16 + lrow) * 64 + kk * 32 + kgrp * 8];
#pragma unroll
            for (int m = 0; m < 4; ++m)
#pragma unroll
                for (int n = 0; n < 4; ++n)
                    acc[m][n] = MFMA16(af[m], bfr[n], acc[m][n]);
        }
        __syncthreads();
    }
}

// ---------------------------------------------------------------------------
// 8-phase 256x256 core (tv, scores). 512 threads = 8 waves (2x4).
// LDS per operand: [2 buf][256 rows][64 elems] (128-B rows), 16-B-granule
// XOR swizzle phys = logical ^ (row&7), rule #21 both-sides.
// Stage map: P1: B(t+1) lo, P2: B(t+1) hi, P4: A(t+2) lo+hi, vmcnt(4).
// ---------------------------------------------------------------------------
__device__ __forceinline__ void mma256(
    const ushort* __restrict__ A, int lda, int abase,
    const ushort* __restrict__ B, int ldb, int bbase,
    int NT, ushort* As, ushort* Bs, f32x4 (&acc)[8][4])
{
    const int tid  = threadIdx.x;
    const int lane = tid & 63, w = tid >> 6;
    const int wr = w >> 2, wc = w & 3;
    const int lrow = lane & 15, kgrp = lane >> 4;
    const int sgl  = ((lane & 7) ^ ((lane >> 3) & 7)) * 8;  // pre-swizzled src granule
    const int srow = lane >> 3;                             // row within 8-row chunk

    auto stage = [&](int t, int isB, int hi) {
        const ushort* src = isB ? B : A;
        const int ld = isB ? ldb : lda;
        const int rb = isB ? bbase : abase;
        ushort* buf = (isB ? Bs : As) + (size_t)(t & 1) * 16384;
#pragma unroll
        for (int i = 0; i < 2; ++i) {
            const int r = hi * 128 + (w * 2 + i) * 8 + srow;
            async16(&src[(size_t)(rb + r) * ld + t * 64 + sgl],
                    buf + (size_t)(hi * 128 + (w * 2 + i) * 8) * 64 + lane * 8);
        }
    };

#pragma unroll
    for (int m = 0; m < 8; ++m)
#pragma unroll
        for (int n = 0; n < 4; ++n) acc[m][n] = (f32x4){0.f, 0.f, 0.f, 0.f};

    stage(0, 0, 0); stage(0, 0, 1); stage(0, 1, 0); stage(0, 1, 1);
    if (NT > 1) {
        stage(1, 0, 0); stage(1, 0, 1);
        asm volatile("s_waitcnt vmcnt(4)" ::: "memory");
    } else {
        asm volatile("s_waitcnt vmcnt(0)" ::: "memory");
    }
    SCHED();
    SBAR();
    SCHED();

    const int sw = lrow & 7;

    for (int t = 0; t < NT; ++t) {
        ushort* Ab = As + (size_t)(t & 1) * 16384;
        ushort* Bb = Bs + (size_t)(t & 1) * 16384;
        bf16x8 af[8], bfr[2];

        // ---- P1: (kk0, n0-1) ----
        {
            const int g = (kgrp ^ sw) * 8;
#pragma unroll
            for (int m = 0; m < 8; ++m)
                af[m] = *(const bf16x8*)&Ab[(wr * 128 + m * 16 + lrow) * 64 + g];
#pragma unroll
            for (int n = 0; n < 2; ++n)
                bfr[n] = *(const bf16x8*)&Bb[(wc * 64 + n * 16 + lrow) * 64 + g];
        }
        if (t + 1 < NT) stage(t + 1, 1, 0);
        SBAR(); SCHED();
        __builtin_amdgcn_s_setprio(1);
#pragma unroll
        for (int m = 0; m < 8; ++m) {
            acc[m][0] = MFMA16(af[m], bfr[0], acc[m][0]);
            acc[m][1] = MFMA16(af[m], bfr[1], acc[m][1]);
        }
        __builtin_amdgcn_s_setprio(0);
        SBAR(); SCHED();

        // ---- P2: (kk0, n2-3) ----
        {
            const int g = (kgrp ^ sw) * 8;
#pragma unroll
            for (int n = 0; n < 2; ++n)
                bfr[n] = *(const bf16x8*)&Bb[(wc * 64 + (2 + n) * 16 + lrow) * 64 + g];
        }
        if (t + 1 < NT) stage(t + 1, 1, 1);
        SBAR(); SCHED();
        __builtin_amdgcn_s_setprio(1);
#pragma unroll
        for (int m = 0; m < 8; ++m) {
            acc[m][2] = MFMA16(af[m], bfr[0], acc[m][2]);
            acc[m][3] = MFMA16(af[m], bfr[1], acc[m][3]);
        }
        __builtin_amdgcn_s_setprio(0);
        SBAR(); SCHED();

        // ---- P3: (kk1, n0-1) ----
        {
            const int g = ((4 + kgrp) ^ sw) * 8;
#pragma unroll
            for (int m = 0; m < 8; ++m)
                af[m] = *(const bf16x8*)&Ab[(wr * 128 + m * 16 + lrow) * 64 + g];
#pragma unroll
            for (int n = 0; n < 2; ++n)
                bfr[n] = *(const bf16x8*)&Bb[(wc * 64 + n * 16 + lrow) * 64 + g];
        }
        SBAR(); SCHED();
        __builtin_amdgcn_s_setprio(1);
#pragma unroll
        for (int m = 0; m < 8; ++m) {
            acc[m][0] = MFMA16(af[m], bfr[0], acc[m][0]);
            acc[m][1] = MFMA16(af[m], bfr[1], acc[m][1]);
        }
        __builtin_amdgcn_s_setprio(0);
        SBAR(); SCHED();

        // ---- P4: (kk1, n2-3) ----
        {
            const int g = ((4 + kgrp) ^ sw) * 8;
#pragma unroll
            for (int n = 0; n < 2; ++n)
                bfr[n] = *(const bf16x8*)&Bb[(wc * 64 + (2 + n) * 16 + lrow) * 64 + g];
        }
        if (t + 2 < NT) {
            stage(t + 2, 0, 0); stage(t + 2, 0, 1);
            asm volatile("s_waitcnt vmcnt(4)" ::: "memory");
        } else if (t + 1 < NT) {
            asm volatile("s_waitcnt vmcnt(0)" ::: "memory");
        }
        SCHED();
        SBAR(); SCHED();
        __builtin_amdgcn_s_setprio(1);
#pragma unroll
        for (int m = 0; m < 8; ++m) {
            acc[m][2] = MFMA16(af[m], bfr[0], acc[m][2]);
            acc[m][3] = MFMA16(af[m], bfr[1], acc[m][3]);
        }
        __builtin_amdgcn_s_setprio(0);
        SBAR(); SCHED();
    }
}

// ---------------------------------------------------------------------------
// Kernel 1: Mtr[f][d] = (sum_e Wkt[f][e] * Wqt[d][e]) / 32  (scale folded).
// ---------------------------------------------------------------------------
__global__ __launch_bounds__(256) void m_gemm(
    const ushort* __restrict__ Wkt, const ushort* __restrict__ Wqt,
    ushort* __restrict__ Mtr)
{
    __shared__ ushort As[128 * 64];
    __shared__ ushort Bs[128 * 64];
    const int fbase = blockIdx.x * 128;
    const int dbase = blockIdx.y * 128;

    f32x4 acc[4][4];
    mma_tile(Wkt, 1024, fbase, Wqt, 1024, dbase, 16, As, Bs, acc);

    const int lane = threadIdx.x & 63, wid = threadIdx.x >> 6;
    const int wr = wid >> 1, wc = wid & 1;
    const int lrow = lane & 15, kgrp = lane >> 4;
#pragma unroll
    for (int m = 0; m < 4; ++m)
#pragma unroll
        for (int n = 0; n < 4; ++n)
#pragma unroll
            for (int r = 0; r < 4; ++r) {
                const int gf = fbase + wr * 64 + m * 16 + kgrp * 4 + r;
                const int gd = dbase + wc * 64 + n * 16 + lrow;
                Mtr[(size_t)gf * 1024 + gd] = f2bf(acc[m][n][r] * 0.03125f);
            }
}

// ---------------------------------------------------------------------------
// Kernel 2: 8-phase. z=0: T = xb @ Mtr^T -> Tb row-major. z=1: V -> Vt transposed.
// ---------------------------------------------------------------------------
__global__ __launch_bounds__(512, 2) void tv_gemm8(
    const ushort* __restrict__ xb, const ushort* __restrict__ Mtr,
    const ushort* __restrict__ Wvb,
    ushort* __restrict__ Tb, ushort* __restrict__ Vt)
{
    __shared__ ushort As[2 * 16384];
    __shared__ ushort Bs[2 * 16384];

    const int z = blockIdx.z;
    const ushort* Bmat = z ? Wvb : Mtr;
    const int mbase = blockIdx.x * 256;
    const int nbase = blockIdx.y * 256;

    f32x4 acc[8][4];
    mma256(xb, 1024, mbase, Bmat, 1024, nbase, 16, As, Bs, acc);

    const int lane = threadIdx.x & 63, w = threadIdx.x >> 6;
    const int wr = w >> 2, wc = w & 3;
    const int lrow = lane & 15, kgrp = lane >> 4;

    if (z == 1) {
        const int b  = mbase >> 11;
        const int s0 = mbase & 2047;
        ushort* VtB = Vt + (size_t)b * 1024 * 2048;
#pragma unroll
        for (int m = 0; m < 8; ++m)
#pragma unroll
            for (int n = 0; n < 4; ++n) {
                u16x4 pk;
#pragma unroll
                for (int r = 0; r < 4; ++r) pk[r] = f2bf(acc[m][n][r]);
                const int d = nbase + wc * 64 + n * 16 + lrow;
                const int s = s0 + wr * 128 + m * 16 + kgrp * 4;
                *(u16x4*)&VtB[(size_t)d * 2048 + s] = pk;
            }
    } else {
#pragma unroll
        for (int m = 0; m < 8; ++m)
#pragma unroll
            for (int n = 0; n < 4; ++n)
#pragma unroll
                for (int r = 0; r < 4; ++r) {
                    const int gr = mbase + wr * 128 + m * 16 + kgrp * 4 + r;
                    const int gc = nbase + wc * 64 + n * 16 + lrow;
                    Tb[(size_t)gr * 1024 + gc] = f2bf(acc[m][n][r]);
                }
    }
}

// ---------------------------------------------------------------------------
// Kernel 3: 8-phase scores, lower-tri 256-tiles. Stores UNNORMALIZED
// p = exp(s) with causal mask, AND writes per-(row, jt) partial row-sums
// rsum[b][jt][row] (exactly one writer each -> deterministic).
// ---------------------------------------------------------------------------
__global__ __launch_bounds__(512, 2) void scores_gemm8(
    const ushort* __restrict__ Tb, const ushort* __restrict__ xb,
    ushort* __restrict__ Sall, float* __restrict__ rsum)
{
    __shared__ ushort As[2 * 16384];
    __shared__ ushort Bs[2 * 16384];

    ushort* S = Sall + (size_t)blockIdx.y * 2048 * 2048;
    const int rb = blockIdx.y * 2048;

    int t = blockIdx.x;
    int it = (int)((sqrtf(8.0f * (float)t + 1.0f) - 1.0f) * 0.5f);
    while ((it + 1) * (it + 2) / 2 <= t) ++it;
    while (it * (it + 1) / 2 > t) --it;
    const int jt = t - it * (it + 1) / 2;
    const int ibase = it * 256, jbase = jt * 256;
    const bool diag = (it == jt);

    f32x4 acc[8][4];
    mma256(Tb, 1024, rb + ibase, xb, 1024, rb + jbase, 16, As, Bs, acc);

    const int tid = threadIdx.x;
    const int lane = tid & 63, w = tid >> 6;
    const int wr = w >> 2, wc = w & 3;
    const int lrow = lane & 15, kgrp = lane >> 4;

    float prs[8][4];
#pragma unroll
    for (int m = 0; m < 8; ++m)
#pragma unroll
        for (int r = 0; r < 4; ++r) prs[m][r] = 0.f;

#pragma unroll
    for (int m = 0; m < 8; ++m)
#pragma unroll
        for (int n = 0; n < 4; ++n)
#pragma unroll
            for (int r = 0; r < 4; ++r) {
                const int gi = ibase + wr * 128 + m * 16 + kgrp * 4 + r;
                const int gj = jbase + wc * 64 + n * 16 + lrow;
                float p = __expf(acc[m][n][r]);
                if (diag && gj > gi) p = 0.f;
                S[(size_t)gi * 2048 + gj] = f2bf(p);
                prs[m][r] += p;
            }

    // reduce partial sums over lrow (16 lanes), stash per-wave slice in LDS
    float* psum = (float*)As;   // [2 wr][4 wc][128 rows] = 4 KB (As is dead)
#pragma unroll
    for (int m = 0; m < 8; ++m)
#pragma unroll
        for (int r = 0; r < 4; ++r) {
            float v = prs[m][r];
            v += __shfl_xor(v, 1);
            v += __shfl_xor(v, 2);
            v += __shfl_xor(v, 4);
            v += __shfl_xor(v, 8);
            prs[m][r] = v;
        }
    if (lrow == 0) {
#pragma unroll
        for (int m = 0; m < 8; ++m)
#pragma unroll
            for (int r = 0; r < 4; ++r)
                psum[(wr * 4 + wc) * 128 + m * 16 + kgrp * 4 + r] = prs[m][r];
    }
    __syncthreads();
    if (tid < 256) {
        const int half = tid >> 7, rr = tid & 127;
        float s4 = psum[(half * 4 + 0) * 128 + rr] + psum[(half * 4 + 1) * 128 + rr]
                 + psum[(half * 4 + 2) * 128 + rr] + psum[(half * 4 + 3) * 128 + rr];
        rsum[(size_t)(blockIdx.y * 9 + jt) * 2048 + ibase + tid] = s4;
    }
}

// ---------------------------------------------------------------------------
// PV sub-GEMM: O-rows [it*128, +128) x cols [nbase, +128). Fat single-phase,
// 3-deep prefetch (3 LDS buffers; stage(t+3) lands in the just-released slot).
// stage() = 4 loads/thread. Ledger: at the in-loop wait, outstanding =
// {t+1,t+2,t+3} x 4 = 12 -> vmcnt(8) completes t+1 (two iterations of
// latency cover). Prologue: 3 tiles staged (12) -> vmcnt(8) completes tile 0.
// Tails: t+3==NT -> 8 outstanding, vmcnt(4); t+2==NT -> 4, vmcnt(0).
// XOR-16B swizzled LDS. Row normalization from precomputed rsum partials.
// ---------------------------------------------------------------------------
__device__ __forceinline__ void pv_sub(
    const ushort* __restrict__ P, const ushort* __restrict__ Vt,
    float* __restrict__ O, const float* __restrict__ rsb,
    int it, int nbase, ushort* As, ushort* Bs, float* rs)
{
    const int tid  = threadIdx.x;
    const int lane = tid & 63, w = tid >> 6;
    const int wr = w >> 2, wc = w & 3;
    const int lrow = lane & 15, kgrp = lane >> 4;
    const int srow = lane >> 3;
    const int sc16 = (lane & 7) ^ srow;
    const int pbase = it * 128;
    const int NT = 2 * (it + 1);
    const int jtmax = it >> 1;

    auto stage = [&](int t, int slot) {
        ushort* dA = As + (size_t)slot * 8192;
        ushort* dB = Bs + (size_t)slot * 8192;
#pragma unroll
        for (int i = 0; i < 2; ++i) {
            const int rr = (i * 8 + w) * 8 + srow;
            async16(&P [(size_t)(pbase + rr) * 2048 + t * 64 + sc16 * 8],
                    dA + ((i * 8 + w) * 64 + lane) * 8);
            async16(&Vt[(size_t)(nbase + rr) * 2048 + t * 64 + sc16 * 8],
                    dB + ((i * 8 + w) * 64 + lane) * 8);
        }
    };

    // precompute row normalizers (<= 9 partials per row)
    if (tid < 128) {
        float s = 0.f;
        for (int j = 0; j <= jtmax; ++j)
            s += rsb[(size_t)j * 2048 + pbase + tid];
        rs[tid] = 1.0f / s;
    }

    f32x4 acc[4][2];
#pragma unroll
    for (int m = 0; m < 4; ++m)
#pragma unroll
        for (int n = 0; n < 2; ++n) acc[m][n] = (f32x4){0.f, 0.f, 0.f, 0.f};

    stage(0, 0);
    if (NT > 2) {
        stage(1, 1); stage(2, 2);
        asm volatile("s_waitcnt vmcnt(8)" ::: "memory");   // tile 0 resident
    } else {   // NT == 2
        stage(1, 1);
        asm volatile("s_waitcnt vmcnt(4)" ::: "memory");   // tile 0 resident
    }
    SCHED();
    SBAR(); SCHED();

    int bi = 0;
    for (int t = 0; t < NT; ++t) {
        const ushort* Ab = As + (size_t)bi * 8192;
        const ushort* Bb = Bs + (size_t)bi * 8192;
        bf16x8 af[2][4], bq[2][2];
#pragma unroll
        for (int kk = 0; kk < 2; ++kk) {
            const int p16 = (kk * 4 + kgrp) ^ (lrow & 7);
#pragma unroll
            for (int m = 0; m < 4; ++m) {
                const int row = wr * 64 + m * 16 + lrow;
                af[kk][m] = *(const bf16x8*)&Ab[row * 64 + p16 * 8];
            }
#pragma unroll
            for (int n = 0; n < 2; ++n) {
                const int row = wc * 32 + n * 16 + lrow;
                bq[kk][n] = *(const bf16x8*)&Bb[row * 64 + p16 * 8];
            }
        }
        asm volatile("s_waitcnt lgkmcnt(0)" ::: "memory");
        SCHED();
        SBAR(); SCHED();                   // buf[bi] fully read -> released
        if (t + 3 < NT) {
            stage(t + 3, bi);
            asm volatile("s_waitcnt vmcnt(8)" ::: "memory");  // t+1 complete
        } else if (t + 3 == NT) {
            asm volatile("s_waitcnt vmcnt(4)" ::: "memory");  // t+1 complete
        } else if (t + 2 == NT) {
            asm volatile("s_waitcnt vmcnt(0)" ::: "memory");  // t+1 complete
        }
        SCHED();
        SBAR(); SCHED();                   // t+1 resident for all waves
        __builtin_amdgcn_s_setprio(1);
#pragma unroll
        for (int kk = 0; kk < 2; ++kk)
#pragma unroll
            for (int m = 0; m < 4; ++m) {
                acc[m][0] = MFMA16(af[kk][m], bq[kk][0], acc[m][0]);
                acc[m][1] = MFMA16(af[kk][m], bq[kk][1], acc[m][1]);
            }
        __builtin_amdgcn_s_setprio(0);
        bi = (bi == 2) ? 0 : bi + 1;
    }

    __syncthreads();   // rs[] ready (written pre-loop by tid<128)

#pragma unroll
    for (int m = 0; m < 4; ++m)
#pragma unroll
        for (int r = 0; r < 4; ++r) {
            const int ri = wr * 64 + m * 16 + kgrp * 4 + r;
            const float inv = rs[ri];
            const int gi = pbase + ri;
#pragma unroll
            for (int n = 0; n < 2; ++n) {
                const int gc = nbase + wc * 32 + n * 16 + lrow;
                O[(size_t)gi * 1024 + gc] = acc[m][n][r] * inv;
            }
        }
    __syncthreads();
}

// ---------------------------------------------------------------------------
// Kernel 4: O = P @ V with fused normalize. Paired row-tiles (15-bx, bx):
// every block exactly 34 k-tiles. grid (8, 8, 4) = 256 blocks = 1/CU.
// ---------------------------------------------------------------------------
__global__ __launch_bounds__(512, 2) void pv_pair(
    const ushort* __restrict__ Pall, const ushort* __restrict__ Vtall,
    const float* __restrict__ rsum, float* __restrict__ Oall)
{
    __shared__ ushort As[3 * 8192];   // 48 KiB
    __shared__ ushort Bs[3 * 8192];   // 48 KiB
    __shared__ float rs[128];

    const ushort* P  = Pall  + (size_t)blockIdx.z * 2048 * 2048;
    const ushort* Vt = Vtall + (size_t)blockIdx.z * 1024 * 2048;
    const float* rsb = rsum  + (size_t)blockIdx.z * 9 * 2048;
    float*        O  = Oall  + (size_t)blockIdx.z * 2048 * 1024;
    const int nbase = blockIdx.y * 128;

    pv_sub(P, Vt, O, rsb, 15 - (int)blockIdx.x, nbase, As, Bs, rs);
    pv_sub(P, Vt, O, rsb, (int)blockIdx.x,      nbase, As, Bs, rs);
}

// ---------------------------------------------------------------------------
extern "C" void kernel_launch(void* const* d_in, const int* in_sizes, int n_in,
                              void* d_out, int out_size, void* d_ws, size_t ws_size,
                              hipStream_t stream)
{
    (void)in_sizes; (void)n_in; (void)out_size; (void)ws_size;
    const float* x  = (const float*)d_in[0];
    const float* Wk = (const float*)d_in[1];
    const float* Wq = (const float*)d_in[2];
    const float* Wv = (const float*)d_in[3];
    float* out = (float*)d_out;

    const size_t M1 = (size_t)1024 * 1024;
    ushort* ws  = (ushort*)d_ws;
    ushort* xb  = ws;                      // 8M elems
    ushort* Tb  = xb  + 8 * M1;            // 8M
    ushort* Vt  = Tb  + 8 * M1;            // 8M (4 x [1024][2048])
    ushort* Sb  = Vt  + 8 * M1;            // 16M (4 x [2048][2048])
    ushort* Wkt = Sb  + 16 * M1;           // 1M
    ushort* Wqt = Wkt + M1;                // 1M
    ushort* Wvb = Wqt + M1;                // 1M
    ushort* Mtr = Wvb + M1;                // 1M
    float*  rsum = (float*)(Mtr + M1);     // 4*9*2048 fp32 = 294 KB

    // 0) fused conversions (x, Wv straight; Wk, Wq transposed)
    cvt_all<<<6656, 256, 0, stream>>>(x, Wk, Wq, Wv, xb, Wvb, Wkt, Wqt);
    // 1) M = (Wq^T Wk)/32 stored transposed
    m_gemm<<<dim3(8, 8), 256, 0, stream>>>(Wkt, Wqt, Mtr);
    // 2) T = x@M (z=0), V^T (z=1); 256 blocks = 1/CU
    tv_gemm8<<<dim3(32, 4, 2), 512, 0, stream>>>(xb, Mtr, Wvb, Tb, Vt);
    // 3) scores -> exp(s) with causal mask + partial row-sums
    scores_gemm8<<<dim3(36, 4), 512, 0, stream>>>(Tb, xb, Sb, rsum);
    // 4) O = P @ V with fused normalize, balanced paired row-tiles
    pv_pair<<<dim3(8, 8, 4), 512, 0, stream>>>(Sb, Vt, rsum, out);
}